// Round 1
// baseline (316.000 us; speedup 1.0000x reference)
//
#include <hip/hip_runtime.h>
#include <hip/hip_bf16.h>

typedef __attribute__((ext_vector_type(8))) short s16x8;
typedef __attribute__((ext_vector_type(4))) float f32x4;

#define MFMA16(a,b,c) __builtin_amdgcn_mfma_f32_16x16x32_bf16((a),(b),(c),0,0,0)

#define GLD16(gp, lp) __builtin_amdgcn_global_load_lds( \
  (const __attribute__((address_space(1))) unsigned int*)(gp), \
  (__attribute__((address_space(3))) unsigned int*)(lp), 16, 0, 0)

static __device__ __forceinline__ unsigned short f2bu(float f) {
  __hip_bfloat16 h = __float2bfloat16(f);
  unsigned short u; __builtin_memcpy(&u, &h, 2); return u;
}
static __device__ __forceinline__ float b2f(unsigned short u) {
  unsigned int x = ((unsigned int)u) << 16; float f; __builtin_memcpy(&f, &x, 4); return f;
}

// ---------------------------------------------------------------- cast f32->bf16
__global__ __launch_bounds__(256) void cast_w(const float* __restrict__ in,
                                              unsigned short* __restrict__ out, int n4) {
  int i = blockIdx.x * 256 + threadIdx.x;
  if (i < n4) {
    float4 v = *(const float4*)(in + (size_t)i * 4);
    unsigned int p0 = (unsigned int)f2bu(v.x) | ((unsigned int)f2bu(v.y) << 16);
    unsigned int p1 = (unsigned int)f2bu(v.z) | ((unsigned int)f2bu(v.w) << 16);
    uint2 pk; pk.x = p0; pk.y = p1;
    *(uint2*)(out + (size_t)i * 4) = pk;
  }
}

// ---------------------------------------------------------------- GEMM: C = A(f32) * Bw(bf16)^T
// A[M][K] f32 row-major, Bw[N][K] bf16 row-major, C[M][N] (float or bf16-as-ushort)
static __device__ __forceinline__ void store_c(float* C, size_t idx, float v) { C[idx] = v; }
static __device__ __forceinline__ void store_c(unsigned short* C, size_t idx, float v) { C[idx] = f2bu(v); }

template <typename OutT>
__global__ __launch_bounds__(256) void gemm_af32_bt(const float* __restrict__ A,
                                                    const unsigned short* __restrict__ Bw,
                                                    OutT* __restrict__ C,
                                                    int M, int N, int K) {
  __shared__ unsigned short As[128][64];  // 16 KB
  __shared__ unsigned short Bs[128][64];  // 16 KB
  const int tid = threadIdx.x;
  const int lane = tid & 63, wave = tid >> 6;
  const int wm = wave >> 1, wn = wave & 1;
  const int row16 = lane & 15, kgrp = lane >> 4;
  const int m0 = blockIdx.y * 128, n0 = blockIdx.x * 128;

  f32x4 acc[4][4] = {};

  for (int k0 = 0; k0 < K; k0 += 64) {
    // stage B tile via async global->LDS (16B/lane, 4 calls per wave)
#pragma unroll
    for (int i = 0; i < 4; i++) {
      int rr = (wave * 4 + i) * 8 + (lane >> 3);
      const unsigned short* gp = Bw + (size_t)(n0 + rr) * K + k0 + (lane & 7) * 8;
      GLD16(gp, (char*)Bs + (wave * 4 + i) * 1024);
    }
    // stage A tile: load f32, convert to bf16, ds_write 8B
    const float* Ag = A + (size_t)m0 * K + k0;
#pragma unroll
    for (int i = 0; i < 8; i++) {
      int f = tid + i * 256;              // 0..2047 float4s
      int r = f >> 4, c4 = (f & 15) * 4;
      float4 v = *(const float4*)(Ag + (size_t)r * K + c4);
      unsigned int p0 = (unsigned int)f2bu(v.x) | ((unsigned int)f2bu(v.y) << 16);
      unsigned int p1 = (unsigned int)f2bu(v.z) | ((unsigned int)f2bu(v.w) << 16);
      uint2 pk; pk.x = p0; pk.y = p1;
      *(uint2*)&As[r][c4] = pk;
    }
    __syncthreads();

#pragma unroll
    for (int kk = 0; kk < 2; kk++) {
      s16x8 af[4], bfr[4];
#pragma unroll
      for (int mi = 0; mi < 4; mi++)
        af[mi] = *(const s16x8*)&As[wm * 64 + mi * 16 + row16][kk * 32 + kgrp * 8];
#pragma unroll
      for (int ni = 0; ni < 4; ni++)
        bfr[ni] = *(const s16x8*)&Bs[wn * 64 + ni * 16 + row16][kk * 32 + kgrp * 8];
#pragma unroll
      for (int mi = 0; mi < 4; mi++)
#pragma unroll
        for (int ni = 0; ni < 4; ni++)
          acc[mi][ni] = MFMA16(af[mi], bfr[ni], acc[mi][ni]);
    }
    __syncthreads();
  }

#pragma unroll
  for (int mi = 0; mi < 4; mi++)
#pragma unroll
    for (int ni = 0; ni < 4; ni++)
#pragma unroll
      for (int r = 0; r < 4; r++) {
        int row = m0 + wm * 64 + mi * 16 + kgrp * 4 + r;
        int col = n0 + wn * 64 + ni * 16 + row16;
        store_c(C, (size_t)row * N + col, acc[mi][ni][r]);
      }
}

// ---------------------------------------------------------------- first unmasked key per batch
__global__ __launch_bounds__(256) void fu_kernel(const int* __restrict__ mask, int* __restrict__ fu) {
  const int S = 2048;
  int b = blockIdx.x;
  __shared__ int red[256];
  int best = S;
  for (int k = threadIdx.x; k < S; k += 256)
    if (mask[b * S + k] != 0 && k < best) best = k;
  red[threadIdx.x] = best;
  __syncthreads();
  for (int s = 128; s > 0; s >>= 1) {
    if (threadIdx.x < s) red[threadIdx.x] = min(red[threadIdx.x], red[threadIdx.x + s]);
    __syncthreads();
  }
  if (threadIdx.x == 0) fu[b] = red[0];
}

// ---------------------------------------------------------------- V column-sum (deterministic 2-stage)
__global__ __launch_bounds__(256) void reduce_v(const unsigned short* __restrict__ V,
                                                float* __restrict__ part) {
  int b = blockIdx.x >> 4, ch = blockIdx.x & 15;
  int c0 = threadIdx.x * 4;
  const unsigned short* p = V + ((size_t)(b * 2048 + ch * 128)) * 1024 + c0;
  float s0 = 0, s1 = 0, s2 = 0, s3 = 0;
  for (int k = 0; k < 128; k++) {
    uint2 u = *(const uint2*)p;
    s0 += b2f((unsigned short)(u.x & 0xffff));
    s1 += b2f((unsigned short)(u.x >> 16));
    s2 += b2f((unsigned short)(u.y & 0xffff));
    s3 += b2f((unsigned short)(u.y >> 16));
    p += 1024;
  }
  float* o = part + ((size_t)blockIdx.x << 10) + c0;
  o[0] = s0; o[1] = s1; o[2] = s2; o[3] = s3;
}

__global__ __launch_bounds__(256) void combine_v(const float* __restrict__ part,
                                                 float* __restrict__ vsum) {
  int i = blockIdx.x * 256 + threadIdx.x;  // 0..2047
  int b = i >> 10, d = i & 1023;
  float s = 0;
#pragma unroll
  for (int ch = 0; ch < 16; ch++) s += part[((size_t)(b * 16 + ch) << 10) + d];
  vsum[i] = s;
}

// ---------------------------------------------------------------- flash attention
// Q/K/V: bf16 [B][S][1024] (head h at cols h*64..h*64+63). O: f32 same layout.
__global__ __launch_bounds__(256) void flash_attn(const unsigned short* __restrict__ Q,
                                                  const unsigned short* __restrict__ Kp,
                                                  const unsigned short* __restrict__ Vp,
                                                  const int* __restrict__ mask,
                                                  const int* __restrict__ fu,
                                                  const float* __restrict__ vsum,
                                                  float* __restrict__ O) {
  const int S = 2048, DM = 1024;
  const int qt = blockIdx.x, bh = blockIdx.y;
  const int b = bh >> 4, h = bh & 15;
  const int tid = threadIdx.x, lane = tid & 63, wave = tid >> 6;
  const int row16 = lane & 15, kgrp = lane >> 4;

  __shared__ unsigned short Ks[64][64];      // 8 KB, linear (global_load_lds)
  __shared__ unsigned short Vs[64][72];      // V^T [d][k], padded rows (144B = 16B-mult)
  __shared__ unsigned short Ps[4][16][72];   // per-wave P, padded

  const int q0 = qt * 64 + wave * 16;
  const size_t base = ((size_t)b * S) * DM + h * 64;

  s16x8 qf[2];
#pragma unroll
  for (int kk = 0; kk < 2; kk++)
    qf[kk] = *(const s16x8*)&Q[base + (size_t)(q0 + row16) * DM + kk * 32 + kgrp * 8];

  f32x4 oacc[4] = {};
  float m_run[4], l_run[4];
#pragma unroll
  for (int r = 0; r < 4; r++) { m_run[r] = -1e30f; l_run[r] = 0.f; }

  const int* maskb = mask + b * S;
  const int ntiles = qt + 1;

  for (int t = 0; t < ntiles; ++t) {
    const int kb = t * 64;
    // stage K (linear, async)
#pragma unroll
    for (int i = 0; i < 2; i++) {
      int rr = (wave * 2 + i) * 8 + (lane >> 3);
      const unsigned short* gp = Kp + base + (size_t)(kb + rr) * DM + (lane & 7) * 8;
      GLD16(gp, (char*)Ks + (wave * 2 + i) * 1024);
    }
    // stage V transposed
    {
      int vr = tid & 63, vc0 = (tid >> 6) * 16;
      const unsigned short* gp = Vp + base + (size_t)(kb + vr) * DM + vc0;
      s16x8 v0 = *(const s16x8*)gp;
      s16x8 v1 = *(const s16x8*)(gp + 8);
#pragma unroll
      for (int j = 0; j < 8; j++) Vs[vc0 + j][vr] = (unsigned short)v0[j];
#pragma unroll
      for (int j = 0; j < 8; j++) Vs[vc0 + 8 + j][vr] = (unsigned short)v1[j];
    }
    __syncthreads();

    // QK^T
    f32x4 sc[4];
#pragma unroll
    for (int nf = 0; nf < 4; nf++) {
      f32x4 a = {};
      s16x8 k0f = *(const s16x8*)&Ks[nf * 16 + row16][kgrp * 8];
      s16x8 k1f = *(const s16x8*)&Ks[nf * 16 + row16][32 + kgrp * 8];
      a = MFMA16(qf[0], k0f, a);
      a = MFMA16(qf[1], k1f, a);
      sc[nf] = a;
    }
    // scale + pad mask + causal (exact NEG = -10000 semantics)
#pragma unroll
    for (int nf = 0; nf < 4; nf++) {
      int kg = kb + nf * 16 + row16;
      int mv = maskb[kg];
#pragma unroll
      for (int r = 0; r < 4; r++) {
        int qg = q0 + kgrp * 4 + r;
        float s = sc[nf][r] * 0.125f;
        sc[nf][r] = (kg > qg || mv == 0) ? -10000.0f : s;
      }
    }
    // online softmax (row = 16-lane group x reg)
    float tmax[4];
#pragma unroll
    for (int r = 0; r < 4; r++)
      tmax[r] = fmaxf(fmaxf(sc[0][r], sc[1][r]), fmaxf(sc[2][r], sc[3][r]));
#pragma unroll
    for (int d = 1; d < 16; d <<= 1)
#pragma unroll
      for (int r = 0; r < 4; r++) tmax[r] = fmaxf(tmax[r], __shfl_xor(tmax[r], d));

    float mnew[4], alpha[4], rsum[4];
#pragma unroll
    for (int r = 0; r < 4; r++) {
      mnew[r] = fmaxf(m_run[r], tmax[r]);
      alpha[r] = __expf(m_run[r] - mnew[r]);
      m_run[r] = mnew[r];
      rsum[r] = 0.f;
    }
#pragma unroll
    for (int nf = 0; nf < 4; nf++)
#pragma unroll
      for (int r = 0; r < 4; r++) {
        float p = __expf(sc[nf][r] - mnew[r]);
        sc[nf][r] = p;
        rsum[r] += p;
      }
#pragma unroll
    for (int d = 1; d < 16; d <<= 1)
#pragma unroll
      for (int r = 0; r < 4; r++) rsum[r] += __shfl_xor(rsum[r], d);
#pragma unroll
    for (int r = 0; r < 4; r++) l_run[r] = l_run[r] * alpha[r] + rsum[r];
#pragma unroll
    for (int nf2 = 0; nf2 < 4; nf2++)
#pragma unroll
      for (int r = 0; r < 4; r++) oacc[nf2][r] *= alpha[r];

    // P -> LDS (bf16), reload in A-frag layout (wave-local, no barrier needed)
#pragma unroll
    for (int nf = 0; nf < 4; nf++)
#pragma unroll
      for (int r = 0; r < 4; r++)
        Ps[wave][kgrp * 4 + r][nf * 16 + row16] = f2bu(sc[nf][r]);

    s16x8 pf0 = *(const s16x8*)&Ps[wave][row16][kgrp * 8];
    s16x8 pf1 = *(const s16x8*)&Ps[wave][row16][32 + kgrp * 8];
#pragma unroll
    for (int nf2 = 0; nf2 < 4; nf2++) {
      s16x8 v0 = *(const s16x8*)&Vs[nf2 * 16 + row16][kgrp * 8];
      s16x8 v1 = *(const s16x8*)&Vs[nf2 * 16 + row16][32 + kgrp * 8];
      oacc[nf2] = MFMA16(pf0, v0, oacc[nf2]);
      oacc[nf2] = MFMA16(pf1, v1, oacc[nf2]);
    }
    __syncthreads();
  }

  // epilogue: normalize; rows before first unmasked key get uniform mean over ALL 2048 V rows
  const int fub = fu[b];
  const float* vs = vsum + b * DM + h * 64;
#pragma unroll
  for (int nf2 = 0; nf2 < 4; nf2++)
#pragma unroll
    for (int r = 0; r < 4; r++) {
      int qg = q0 + kgrp * 4 + r;
      int d = nf2 * 16 + row16;
      float val = oacc[nf2][r] / l_run[r];
      if (qg < fub) val = vs[d] * (1.0f / 2048.0f);
      O[base + (size_t)qg * DM + d] = val;
    }
}

// ---------------------------------------------------------------- launch
extern "C" void kernel_launch(void* const* d_in, const int* in_sizes, int n_in,
                              void* d_out, int out_size, void* d_ws, size_t ws_size,
                              hipStream_t stream) {
  const float* q    = (const float*)d_in[0];
  const float* k    = (const float*)d_in[1];
  const float* v    = (const float*)d_in[2];
  const int*   mask = (const int*)d_in[3];
  const float* Wq   = (const float*)d_in[4];
  const float* Wk   = (const float*)d_in[5];
  const float* Wv   = (const float*)d_in[6];
  const float* Wo   = (const float*)d_in[7];
  float* out = (float*)d_out;
  char* ws = (char*)d_ws;

  unsigned short* Wqb = (unsigned short*)(ws + (size_t)0);
  unsigned short* Wkb = (unsigned short*)(ws + ((size_t)2 << 20));
  unsigned short* Wvb = (unsigned short*)(ws + ((size_t)4 << 20));
  unsigned short* Wob = (unsigned short*)(ws + ((size_t)6 << 20));
  unsigned short* Qb  = (unsigned short*)(ws + ((size_t)8 << 20));
  unsigned short* Kb  = (unsigned short*)(ws + ((size_t)16 << 20));
  unsigned short* Vb  = (unsigned short*)(ws + ((size_t)24 << 20));
  float* attn = (float*)(ws + ((size_t)32 << 20));
  float* part = (float*)(ws + ((size_t)48 << 20));
  float* vsum = (float*)(ws + ((size_t)48 << 20) + (128 << 10));
  int*   fub  = (int*)(ws + ((size_t)48 << 20) + (136 << 10));

  // weights f32 -> bf16
  cast_w<<<1024, 256, 0, stream>>>(Wq, Wqb, 262144);
  cast_w<<<1024, 256, 0, stream>>>(Wk, Wkb, 262144);
  cast_w<<<1024, 256, 0, stream>>>(Wv, Wvb, 262144);
  cast_w<<<1024, 256, 0, stream>>>(Wo, Wob, 262144);

  dim3 gg(8, 32);  // N/128, M/128
  gemm_af32_bt<unsigned short><<<gg, 256, 0, stream>>>(q, Wqb, Qb, 4096, 1024, 1024);
  gemm_af32_bt<unsigned short><<<gg, 256, 0, stream>>>(k, Wkb, Kb, 4096, 1024, 1024);
  gemm_af32_bt<unsigned short><<<gg, 256, 0, stream>>>(v, Wvb, Vb, 4096, 1024, 1024);

  fu_kernel<<<2, 256, 0, stream>>>(mask, fub);
  reduce_v<<<32, 256, 0, stream>>>(Vb, part);
  combine_v<<<8, 256, 0, stream>>>(part, vsum);

  flash_attn<<<dim3(32, 32), 256, 0, stream>>>(Qb, Kb, Vb, mask, fub, vsum, attn);

  gemm_af32_bt<float><<<gg, 256, 0, stream>>>(attn, Wob, out, 4096, 1024, 1024);
}

// Round 2
// 249.779 us; speedup vs baseline: 1.2651x; 1.2651x over previous
//
#include <hip/hip_runtime.h>
#include <hip/hip_bf16.h>

typedef __attribute__((ext_vector_type(8))) short s16x8;
typedef __attribute__((ext_vector_type(4))) float f32x4;

#define MFMA16(a,b,c) __builtin_amdgcn_mfma_f32_16x16x32_bf16((a),(b),(c),0,0,0)

#define GLD16(gp, lp) __builtin_amdgcn_global_load_lds( \
  (const __attribute__((address_space(1))) unsigned int*)(gp), \
  (__attribute__((address_space(3))) unsigned int*)(lp), 16, 0, 0)

static __device__ __forceinline__ unsigned short f2bu(float f) {
  __hip_bfloat16 h = __float2bfloat16(f);
  unsigned short u; __builtin_memcpy(&u, &h, 2); return u;
}
static __device__ __forceinline__ float b2f(unsigned short u) {
  unsigned int x = ((unsigned int)u) << 16; float f; __builtin_memcpy(&f, &x, 4); return f;
}

// ---------------------------------------------------------------- cast all 4 weights, one launch
__global__ __launch_bounds__(256) void cast_w4(const float* __restrict__ w0, const float* __restrict__ w1,
                                               const float* __restrict__ w2, const float* __restrict__ w3,
                                               unsigned short* __restrict__ o0, unsigned short* __restrict__ o1,
                                               unsigned short* __restrict__ o2, unsigned short* __restrict__ o3) {
  const int y = blockIdx.y;
  const float* in = (y == 0) ? w0 : (y == 1) ? w1 : (y == 2) ? w2 : w3;
  unsigned short* out = (y == 0) ? o0 : (y == 1) ? o1 : (y == 2) ? o2 : o3;
  int i = blockIdx.x * 256 + threadIdx.x;   // 0..262143 float4s
  float4 v = *(const float4*)(in + (size_t)i * 4);
  unsigned int p0 = (unsigned int)f2bu(v.x) | ((unsigned int)f2bu(v.y) << 16);
  unsigned int p1 = (unsigned int)f2bu(v.z) | ((unsigned int)f2bu(v.w) << 16);
  uint2 pk; pk.x = p0; pk.y = p1;
  *(uint2*)(out + (size_t)i * 4) = pk;
}

// ---------------------------------------------------------------- shared GEMM core: C = A(f32) * Bw(bf16)^T
// A[M][1024] f32 row-major, Bw[N][1024] bf16 row-major; 128x128 tile, BK=64, 4 waves
static __device__ __forceinline__ void gemm_core(const float* __restrict__ A,
                                                 const unsigned short* __restrict__ Bw,
                                                 int m0, int n0,
                                                 f32x4 (&acc)[4][4],
                                                 unsigned short (*As)[64], unsigned short (*Bs)[64]) {
  const int K = 1024;
  const int tid = threadIdx.x;
  const int lane = tid & 63, wave = tid >> 6;
  const int wm = wave >> 1, wn = wave & 1;
  const int row16 = lane & 15, kgrp = lane >> 4;

  for (int k0 = 0; k0 < K; k0 += 64) {
    // stage B tile via async global->LDS (16B/lane)
#pragma unroll
    for (int i = 0; i < 4; i++) {
      int rr = (wave * 4 + i) * 8 + (lane >> 3);
      const unsigned short* gp = Bw + (size_t)(n0 + rr) * K + k0 + (lane & 7) * 8;
      GLD16(gp, (char*)Bs + (wave * 4 + i) * 1024);
    }
    // stage A tile: load f32, convert to bf16, ds_write 8B
    const float* Ag = A + (size_t)m0 * K + k0;
#pragma unroll
    for (int i = 0; i < 8; i++) {
      int f = tid + i * 256;              // 0..2047 float4s
      int r = f >> 4, c4 = (f & 15) * 4;
      float4 v = *(const float4*)(Ag + (size_t)r * K + c4);
      unsigned int p0 = (unsigned int)f2bu(v.x) | ((unsigned int)f2bu(v.y) << 16);
      unsigned int p1 = (unsigned int)f2bu(v.z) | ((unsigned int)f2bu(v.w) << 16);
      uint2 pk; pk.x = p0; pk.y = p1;
      *(uint2*)&As[r][c4] = pk;
    }
    __syncthreads();

#pragma unroll
    for (int kk = 0; kk < 2; kk++) {
      s16x8 af[4], bfr[4];
#pragma unroll
      for (int mi = 0; mi < 4; mi++)
        af[mi] = *(const s16x8*)&As[wm * 64 + mi * 16 + row16][kk * 32 + kgrp * 8];
#pragma unroll
      for (int ni = 0; ni < 4; ni++)
        bfr[ni] = *(const s16x8*)&Bs[wn * 64 + ni * 16 + row16][kk * 32 + kgrp * 8];
#pragma unroll
      for (int mi = 0; mi < 4; mi++)
#pragma unroll
        for (int ni = 0; ni < 4; ni++)
          acc[mi][ni] = MFMA16(af[mi], bfr[ni], acc[mi][ni]);
    }
    __syncthreads();
  }
}

// fused Q/K/V projection; z=0 -> Qb linear, z=1 -> Kb linear, z=2 -> Vt transposed [b*1024+n][2048]
__global__ __launch_bounds__(256) void qkv_gemm(const float* __restrict__ q, const float* __restrict__ k,
                                                const float* __restrict__ v,
                                                const unsigned short* __restrict__ Wqb,
                                                const unsigned short* __restrict__ Wkb,
                                                const unsigned short* __restrict__ Wvb,
                                                unsigned short* __restrict__ Qb,
                                                unsigned short* __restrict__ Kb,
                                                unsigned short* __restrict__ Vt) {
  __shared__ unsigned short As[128][64];
  __shared__ unsigned short Bs[128][64];
  const int z = blockIdx.z;
  const float* A = (z == 0) ? q : (z == 1) ? k : v;
  const unsigned short* Bw = (z == 0) ? Wqb : (z == 1) ? Wkb : Wvb;
  const int m0 = blockIdx.y * 128, n0 = blockIdx.x * 128;

  f32x4 acc[4][4] = {};
  gemm_core(A, Bw, m0, n0, acc, As, Bs);

  const int lane = threadIdx.x & 63, wave = threadIdx.x >> 6;
  const int wm = wave >> 1, wn = wave & 1;
  const int row16 = lane & 15, kgrp = lane >> 4;

  if (z < 2) {
    unsigned short* C = z ? Kb : Qb;
#pragma unroll
    for (int mi = 0; mi < 4; mi++)
#pragma unroll
      for (int ni = 0; ni < 4; ni++)
#pragma unroll
        for (int r = 0; r < 4; r++) {
          int row = m0 + wm * 64 + mi * 16 + kgrp * 4 + r;
          int col = n0 + wn * 64 + ni * 16 + row16;
          C[(size_t)row * 1024 + col] = f2bu(acc[mi][ni][r]);
        }
  } else {
#pragma unroll
    for (int mi = 0; mi < 4; mi++)
#pragma unroll
      for (int ni = 0; ni < 4; ni++) {
        int mb = m0 + wm * 64 + mi * 16 + kgrp * 4;
        int col = n0 + wn * 64 + ni * 16 + row16;
        int bb = mb >> 11, s = mb & 2047;
        unsigned int p0 = (unsigned int)f2bu(acc[mi][ni][0]) | ((unsigned int)f2bu(acc[mi][ni][1]) << 16);
        unsigned int p1 = (unsigned int)f2bu(acc[mi][ni][2]) | ((unsigned int)f2bu(acc[mi][ni][3]) << 16);
        uint2 pk; pk.x = p0; pk.y = p1;
        *(uint2*)&Vt[(((size_t)(bb * 1024 + col)) << 11) + s] = pk;
      }
  }
}

// output projection: out = attn(f32) * Wo(bf16)^T, f32 out
__global__ __launch_bounds__(256) void gemm_wo(const float* __restrict__ A,
                                               const unsigned short* __restrict__ Bw,
                                               float* __restrict__ C) {
  __shared__ unsigned short As[128][64];
  __shared__ unsigned short Bs[128][64];
  const int m0 = blockIdx.y * 128, n0 = blockIdx.x * 128;
  f32x4 acc[4][4] = {};
  gemm_core(A, Bw, m0, n0, acc, As, Bs);

  const int lane = threadIdx.x & 63, wave = threadIdx.x >> 6;
  const int wm = wave >> 1, wn = wave & 1;
  const int row16 = lane & 15, kgrp = lane >> 4;
#pragma unroll
  for (int mi = 0; mi < 4; mi++)
#pragma unroll
    for (int ni = 0; ni < 4; ni++)
#pragma unroll
      for (int r = 0; r < 4; r++) {
        int row = m0 + wm * 64 + mi * 16 + kgrp * 4 + r;
        int col = n0 + wn * 64 + ni * 16 + row16;
        C[(size_t)row * 1024 + col] = acc[mi][ni][r];
      }
}

// ---------------------------------------------------------------- first unmasked key per batch
__global__ __launch_bounds__(256) void fu_kernel(const int* __restrict__ mask, int* __restrict__ fu) {
  const int S = 2048;
  int b = blockIdx.x;
  __shared__ int red[256];
  int best = S;
  for (int k = threadIdx.x; k < S; k += 256)
    if (mask[b * S + k] != 0 && k < best) best = k;
  red[threadIdx.x] = best;
  __syncthreads();
  for (int s = 128; s > 0; s >>= 1) {
    if (threadIdx.x < s) red[threadIdx.x] = min(red[threadIdx.x], red[threadIdx.x + s]);
    __syncthreads();
  }
  if (threadIdx.x == 0) fu[b] = red[0];
}

// ---------------------------------------------------------------- V column sums from Vt (deterministic)
__global__ __launch_bounds__(256) void reduce_vt(const unsigned short* __restrict__ Vt,
                                                 float* __restrict__ vsum) {
  __shared__ float red[256];
  const unsigned short* p = Vt + ((size_t)blockIdx.x << 11) + threadIdx.x * 8;
  uint4 u = *(const uint4*)p;
  float s = b2f((unsigned short)(u.x & 0xffff));
  s += b2f((unsigned short)(u.x >> 16));
  s += b2f((unsigned short)(u.y & 0xffff));
  s += b2f((unsigned short)(u.y >> 16));
  s += b2f((unsigned short)(u.z & 0xffff));
  s += b2f((unsigned short)(u.z >> 16));
  s += b2f((unsigned short)(u.w & 0xffff));
  s += b2f((unsigned short)(u.w >> 16));
  red[threadIdx.x] = s;
  __syncthreads();
  for (int st = 128; st > 0; st >>= 1) {
    if (threadIdx.x < st) red[threadIdx.x] += red[threadIdx.x + st];
    __syncthreads();
  }
  if (threadIdx.x == 0) vsum[blockIdx.x] = red[0];
}

// ---------------------------------------------------------------- flash attention, no barriers
// Q/K: bf16 [B][S][1024] (head h at cols h*64..). Vt: bf16 [(b*1024+h*64+d)][2048]. O: f32 like Q.
__global__ __launch_bounds__(256) void flash_attn2(const unsigned short* __restrict__ Q,
                                                   const unsigned short* __restrict__ Kp,
                                                   const unsigned short* __restrict__ Vt,
                                                   const int* __restrict__ mask,
                                                   const int* __restrict__ fu,
                                                   const float* __restrict__ vsum,
                                                   float* __restrict__ O) {
  const int S = 2048, DM = 1024;
  const int qt = blockIdx.x, bh = blockIdx.y;
  const int b = bh >> 4, h = bh & 15;
  const int tid = threadIdx.x, lane = tid & 63, wave = tid >> 6;
  const int row16 = lane & 15, kgrp = lane >> 4;

  __shared__ unsigned short Ps[4][16][72];   // per-wave P round-trip only

  const int q0 = qt * 128 + wave * 32;       // this wave's 32 q-rows
  const size_t base = ((size_t)b * S) * DM + h * 64;
  const size_t vtb = ((size_t)(b * 1024 + h * 64)) * S;

  s16x8 qf[2][2];
#pragma unroll
  for (int qi = 0; qi < 2; qi++)
#pragma unroll
    for (int kk = 0; kk < 2; kk++)
      qf[qi][kk] = *(const s16x8*)&Q[base + (size_t)(q0 + qi * 16 + row16) * DM + kk * 32 + kgrp * 8];

  f32x4 oacc[2][4] = {};
  float m_run[2][4], l_run[2][4];
#pragma unroll
  for (int qi = 0; qi < 2; qi++)
#pragma unroll
    for (int r = 0; r < 4; r++) { m_run[qi][r] = -1e30f; l_run[qi][r] = 0.f; }

  const int* maskb = mask + b * S;
  const int ntiles = (q0 + 32 + 63) >> 6;

  for (int t = 0; t < ntiles; ++t) {
    const int kb = t * 64;
    // K fragments straight from global (L2-resident)
    s16x8 kf[4][2];
#pragma unroll
    for (int nf = 0; nf < 4; nf++)
#pragma unroll
      for (int kk = 0; kk < 2; kk++)
        kf[nf][kk] = *(const s16x8*)&Kp[base + (size_t)(kb + nf * 16 + row16) * DM + kk * 32 + kgrp * 8];

    // QK^T
    f32x4 sc[2][4];
#pragma unroll
    for (int qi = 0; qi < 2; qi++)
#pragma unroll
      for (int nf = 0; nf < 4; nf++) {
        f32x4 a = {};
        a = MFMA16(qf[qi][0], kf[nf][0], a);
        a = MFMA16(qf[qi][1], kf[nf][1], a);
        sc[qi][nf] = a;
      }

    // V fragments from transposed Vt (issued early; latency hides under softmax VALU)
    s16x8 vf[4][2];
#pragma unroll
    for (int nf = 0; nf < 4; nf++)
#pragma unroll
      for (int kk = 0; kk < 2; kk++)
        vf[nf][kk] = *(const s16x8*)&Vt[vtb + (size_t)(nf * 16 + row16) * S + kb + kk * 32 + kgrp * 8];

    // scale + pad mask + causal (exact NEG = -10000 semantics)
    int mv[4];
#pragma unroll
    for (int nf = 0; nf < 4; nf++) mv[nf] = maskb[kb + nf * 16 + row16];
#pragma unroll
    for (int qi = 0; qi < 2; qi++)
#pragma unroll
      for (int nf = 0; nf < 4; nf++) {
        int kg = kb + nf * 16 + row16;
#pragma unroll
        for (int r = 0; r < 4; r++) {
          int qg = q0 + qi * 16 + kgrp * 4 + r;
          float s = sc[qi][nf][r] * 0.125f;
          sc[qi][nf][r] = (kg > qg || mv[nf] == 0) ? -10000.0f : s;
        }
      }

    // online softmax per q-frag
#pragma unroll
    for (int qi = 0; qi < 2; qi++) {
      float tmax[4];
#pragma unroll
      for (int r = 0; r < 4; r++)
        tmax[r] = fmaxf(fmaxf(sc[qi][0][r], sc[qi][1][r]), fmaxf(sc[qi][2][r], sc[qi][3][r]));
#pragma unroll
      for (int d = 1; d < 16; d <<= 1)
#pragma unroll
        for (int r = 0; r < 4; r++) tmax[r] = fmaxf(tmax[r], __shfl_xor(tmax[r], d));

      float mnew[4], alpha[4], rsum[4];
#pragma unroll
      for (int r = 0; r < 4; r++) {
        mnew[r] = fmaxf(m_run[qi][r], tmax[r]);
        alpha[r] = __expf(m_run[qi][r] - mnew[r]);
        m_run[qi][r] = mnew[r];
        rsum[r] = 0.f;
      }
#pragma unroll
      for (int nf = 0; nf < 4; nf++)
#pragma unroll
        for (int r = 0; r < 4; r++) {
          float p = __expf(sc[qi][nf][r] - mnew[r]);
          sc[qi][nf][r] = p;
          rsum[r] += p;
        }
#pragma unroll
      for (int d = 1; d < 16; d <<= 1)
#pragma unroll
        for (int r = 0; r < 4; r++) rsum[r] += __shfl_xor(rsum[r], d);
#pragma unroll
      for (int r = 0; r < 4; r++) l_run[qi][r] = l_run[qi][r] * alpha[r] + rsum[r];
#pragma unroll
      for (int nf = 0; nf < 4; nf++)
#pragma unroll
        for (int r = 0; r < 4; r++) oacc[qi][nf][r] *= alpha[r];

      // P -> per-wave LDS (bf16), reload as A-fragments (wave-local, no barrier)
#pragma unroll
      for (int nf = 0; nf < 4; nf++)
#pragma unroll
        for (int r = 0; r < 4; r++)
          Ps[wave][kgrp * 4 + r][nf * 16 + row16] = f2bu(sc[qi][nf][r]);

      s16x8 pf0 = *(const s16x8*)&Ps[wave][row16][kgrp * 8];
      s16x8 pf1 = *(const s16x8*)&Ps[wave][row16][32 + kgrp * 8];
#pragma unroll
      for (int nf2 = 0; nf2 < 4; nf2++) {
        oacc[qi][nf2] = MFMA16(pf0, vf[nf2][0], oacc[qi][nf2]);
        oacc[qi][nf2] = MFMA16(pf1, vf[nf2][1], oacc[qi][nf2]);
      }
    }
  }

  // epilogue: normalize; rows before first unmasked key get uniform mean over ALL 2048 V rows
  const int fub = fu[b];
  const float* vs = vsum + b * DM + h * 64;
#pragma unroll
  for (int qi = 0; qi < 2; qi++)
#pragma unroll
    for (int nf2 = 0; nf2 < 4; nf2++)
#pragma unroll
      for (int r = 0; r < 4; r++) {
        int qg = q0 + qi * 16 + kgrp * 4 + r;
        int d = nf2 * 16 + row16;
        float val = oacc[qi][nf2][r] / l_run[qi][r];
        if (qg < fub) val = vs[d] * (1.0f / 2048.0f);
        O[base + (size_t)qg * DM + d] = val;
      }
}

// ---------------------------------------------------------------- launch
extern "C" void kernel_launch(void* const* d_in, const int* in_sizes, int n_in,
                              void* d_out, int out_size, void* d_ws, size_t ws_size,
                              hipStream_t stream) {
  const float* q    = (const float*)d_in[0];
  const float* k    = (const float*)d_in[1];
  const float* v    = (const float*)d_in[2];
  const int*   mask = (const int*)d_in[3];
  const float* Wq   = (const float*)d_in[4];
  const float* Wk   = (const float*)d_in[5];
  const float* Wv   = (const float*)d_in[6];
  const float* Wo   = (const float*)d_in[7];
  float* out = (float*)d_out;
  char* ws = (char*)d_ws;

  unsigned short* Wqb = (unsigned short*)(ws + (size_t)0);
  unsigned short* Wkb = (unsigned short*)(ws + ((size_t)2 << 20));
  unsigned short* Wvb = (unsigned short*)(ws + ((size_t)4 << 20));
  unsigned short* Wob = (unsigned short*)(ws + ((size_t)6 << 20));
  unsigned short* Qb  = (unsigned short*)(ws + ((size_t)8 << 20));
  unsigned short* Kb  = (unsigned short*)(ws + ((size_t)16 << 20));
  unsigned short* Vt  = (unsigned short*)(ws + ((size_t)24 << 20));
  float* attn = (float*)(ws + ((size_t)32 << 20));
  float* vsum = (float*)(ws + ((size_t)48 << 20));
  int*   fub  = (int*)(ws + ((size_t)48 << 20) + (64 << 10));

  cast_w4<<<dim3(1024, 4), 256, 0, stream>>>(Wq, Wk, Wv, Wo, Wqb, Wkb, Wvb, Wob);

  qkv_gemm<<<dim3(8, 32, 3), 256, 0, stream>>>(q, k, v, Wqb, Wkb, Wvb, Qb, Kb, Vt);

  fu_kernel<<<2, 256, 0, stream>>>(mask, fub);
  reduce_vt<<<2048, 256, 0, stream>>>(Vt, vsum);

  flash_attn2<<<dim3(16, 32), 256, 0, stream>>>(Qb, Kb, Vt, mask, fub, vsum, attn);

  gemm_wo<<<dim3(8, 32), 256, 0, stream>>>(attn, Wob, out);
}

// Round 3
// 242.609 us; speedup vs baseline: 1.3025x; 1.0296x over previous
//
#include <hip/hip_runtime.h>
#include <hip/hip_bf16.h>

typedef __attribute__((ext_vector_type(8))) short s16x8;
typedef __attribute__((ext_vector_type(4))) float f32x4;

#define MFMA16(a,b,c) __builtin_amdgcn_mfma_f32_16x16x32_bf16((a),(b),(c),0,0,0)

#define GLD16(gp, lp) __builtin_amdgcn_global_load_lds( \
  (const __attribute__((address_space(1))) unsigned int*)(gp), \
  (__attribute__((address_space(3))) unsigned int*)(lp), 16, 0, 0)

static __device__ __forceinline__ unsigned short f2bu(float f) {
  __hip_bfloat16 h = __float2bfloat16(f);
  unsigned short u; __builtin_memcpy(&u, &h, 2); return u;
}
static __device__ __forceinline__ float b2f(unsigned short u) {
  unsigned int x = ((unsigned int)u) << 16; float f; __builtin_memcpy(&f, &x, 4); return f;
}

// ---------------------------------------------------------------- cast all 4 weights, one launch
__global__ __launch_bounds__(256) void cast_w4(const float* __restrict__ w0, const float* __restrict__ w1,
                                               const float* __restrict__ w2, const float* __restrict__ w3,
                                               unsigned short* __restrict__ o0, unsigned short* __restrict__ o1,
                                               unsigned short* __restrict__ o2, unsigned short* __restrict__ o3) {
  const int y = blockIdx.y;
  const float* in = (y == 0) ? w0 : (y == 1) ? w1 : (y == 2) ? w2 : w3;
  unsigned short* out = (y == 0) ? o0 : (y == 1) ? o1 : (y == 2) ? o2 : o3;
  int i = blockIdx.x * 256 + threadIdx.x;   // 0..262143 float4s
  float4 v = *(const float4*)(in + (size_t)i * 4);
  unsigned int p0 = (unsigned int)f2bu(v.x) | ((unsigned int)f2bu(v.y) << 16);
  unsigned int p1 = (unsigned int)f2bu(v.z) | ((unsigned int)f2bu(v.w) << 16);
  uint2 pk; pk.x = p0; pk.y = p1;
  *(uint2*)(out + (size_t)i * 4) = pk;
}

// ---------------------------------------------------------------- shared GEMM core: C = A(f32) * Bw(bf16)^T
static __device__ __forceinline__ void gemm_core(const float* __restrict__ A,
                                                 const unsigned short* __restrict__ Bw,
                                                 int m0, int n0,
                                                 f32x4 (&acc)[4][4],
                                                 unsigned short (*As)[64], unsigned short (*Bs)[64]) {
  const int K = 1024;
  const int tid = threadIdx.x;
  const int lane = tid & 63, wave = tid >> 6;
  const int wm = wave >> 1, wn = wave & 1;
  const int row16 = lane & 15, kgrp = lane >> 4;

  for (int k0 = 0; k0 < K; k0 += 64) {
#pragma unroll
    for (int i = 0; i < 4; i++) {
      int rr = (wave * 4 + i) * 8 + (lane >> 3);
      const unsigned short* gp = Bw + (size_t)(n0 + rr) * K + k0 + (lane & 7) * 8;
      GLD16(gp, (char*)Bs + (wave * 4 + i) * 1024);
    }
    const float* Ag = A + (size_t)m0 * K + k0;
#pragma unroll
    for (int i = 0; i < 8; i++) {
      int f = tid + i * 256;
      int r = f >> 4, c4 = (f & 15) * 4;
      float4 v = *(const float4*)(Ag + (size_t)r * K + c4);
      unsigned int p0 = (unsigned int)f2bu(v.x) | ((unsigned int)f2bu(v.y) << 16);
      unsigned int p1 = (unsigned int)f2bu(v.z) | ((unsigned int)f2bu(v.w) << 16);
      uint2 pk; pk.x = p0; pk.y = p1;
      *(uint2*)&As[r][c4] = pk;
    }
    __syncthreads();

#pragma unroll
    for (int kk = 0; kk < 2; kk++) {
      s16x8 af[4], bfr[4];
#pragma unroll
      for (int mi = 0; mi < 4; mi++)
        af[mi] = *(const s16x8*)&As[wm * 64 + mi * 16 + row16][kk * 32 + kgrp * 8];
#pragma unroll
      for (int ni = 0; ni < 4; ni++)
        bfr[ni] = *(const s16x8*)&Bs[wn * 64 + ni * 16 + row16][kk * 32 + kgrp * 8];
#pragma unroll
      for (int mi = 0; mi < 4; mi++)
#pragma unroll
        for (int ni = 0; ni < 4; ni++)
          acc[mi][ni] = MFMA16(af[mi], bfr[ni], acc[mi][ni]);
    }
    __syncthreads();
  }
}

// fused Q/K/V projection; z=0 -> Qb linear, z=1 -> Kb linear, z=2 -> Vt transposed [b*1024+n][2048]
__global__ __launch_bounds__(256) void qkv_gemm(const float* __restrict__ q, const float* __restrict__ k,
                                                const float* __restrict__ v,
                                                const unsigned short* __restrict__ Wqb,
                                                const unsigned short* __restrict__ Wkb,
                                                const unsigned short* __restrict__ Wvb,
                                                unsigned short* __restrict__ Qb,
                                                unsigned short* __restrict__ Kb,
                                                unsigned short* __restrict__ Vt) {
  __shared__ unsigned short As[128][64];
  __shared__ unsigned short Bs[128][64];
  const int z = blockIdx.z;
  const float* A = (z == 0) ? q : (z == 1) ? k : v;
  const unsigned short* Bw = (z == 0) ? Wqb : (z == 1) ? Wkb : Wvb;
  const int m0 = blockIdx.y * 128, n0 = blockIdx.x * 128;

  f32x4 acc[4][4] = {};
  gemm_core(A, Bw, m0, n0, acc, As, Bs);

  const int lane = threadIdx.x & 63, wave = threadIdx.x >> 6;
  const int wm = wave >> 1, wn = wave & 1;
  const int row16 = lane & 15, kgrp = lane >> 4;

  if (z < 2) {
    unsigned short* C = z ? Kb : Qb;
#pragma unroll
    for (int mi = 0; mi < 4; mi++)
#pragma unroll
      for (int ni = 0; ni < 4; ni++)
#pragma unroll
        for (int r = 0; r < 4; r++) {
          int row = m0 + wm * 64 + mi * 16 + kgrp * 4 + r;
          int col = n0 + wn * 64 + ni * 16 + row16;
          C[(size_t)row * 1024 + col] = f2bu(acc[mi][ni][r]);
        }
  } else {
#pragma unroll
    for (int mi = 0; mi < 4; mi++)
#pragma unroll
      for (int ni = 0; ni < 4; ni++) {
        int mb = m0 + wm * 64 + mi * 16 + kgrp * 4;
        int col = n0 + wn * 64 + ni * 16 + row16;
        int bb = mb >> 11, s = mb & 2047;
        unsigned int p0 = (unsigned int)f2bu(acc[mi][ni][0]) | ((unsigned int)f2bu(acc[mi][ni][1]) << 16);
        unsigned int p1 = (unsigned int)f2bu(acc[mi][ni][2]) | ((unsigned int)f2bu(acc[mi][ni][3]) << 16);
        uint2 pk; pk.x = p0; pk.y = p1;
        *(uint2*)&Vt[(((size_t)(bb * 1024 + col)) << 11) + s] = pk;
      }
  }
}

// output projection: out = attn(f32) * Wo(bf16)^T, f32 out
__global__ __launch_bounds__(256) void gemm_wo(const float* __restrict__ A,
                                               const unsigned short* __restrict__ Bw,
                                               float* __restrict__ C) {
  __shared__ unsigned short As[128][64];
  __shared__ unsigned short Bs[128][64];
  const int m0 = blockIdx.y * 128, n0 = blockIdx.x * 128;
  f32x4 acc[4][4] = {};
  gemm_core(A, Bw, m0, n0, acc, As, Bs);

  const int lane = threadIdx.x & 63, wave = threadIdx.x >> 6;
  const int wm = wave >> 1, wn = wave & 1;
  const int row16 = lane & 15, kgrp = lane >> 4;
#pragma unroll
  for (int mi = 0; mi < 4; mi++)
#pragma unroll
    for (int ni = 0; ni < 4; ni++)
#pragma unroll
      for (int r = 0; r < 4; r++) {
        int row = m0 + wm * 64 + mi * 16 + kgrp * 4 + r;
        int col = n0 + wn * 64 + ni * 16 + row16;
        C[(size_t)row * 1024 + col] = acc[mi][ni][r];
      }
}

// ---------------------------------------------------------------- first unmasked key per batch
__global__ __launch_bounds__(256) void fu_kernel(const int* __restrict__ mask, int* __restrict__ fu) {
  const int S = 2048;
  int b = blockIdx.x;
  __shared__ int red[256];
  int best = S;
  for (int k = threadIdx.x; k < S; k += 256)
    if (mask[b * S + k] != 0 && k < best) best = k;
  red[threadIdx.x] = best;
  __syncthreads();
  for (int s = 128; s > 0; s >>= 1) {
    if (threadIdx.x < s) red[threadIdx.x] = min(red[threadIdx.x], red[threadIdx.x + s]);
    __syncthreads();
  }
  if (threadIdx.x == 0) fu[b] = red[0];
}

// ---------------------------------------------------------------- V column sums from Vt (deterministic)
__global__ __launch_bounds__(256) void reduce_vt(const unsigned short* __restrict__ Vt,
                                                 float* __restrict__ vsum) {
  __shared__ float red[256];
  const unsigned short* p = Vt + ((size_t)blockIdx.x << 11) + threadIdx.x * 8;
  uint4 u = *(const uint4*)p;
  float s = b2f((unsigned short)(u.x & 0xffff));
  s += b2f((unsigned short)(u.x >> 16));
  s += b2f((unsigned short)(u.y & 0xffff));
  s += b2f((unsigned short)(u.y >> 16));
  s += b2f((unsigned short)(u.z & 0xffff));
  s += b2f((unsigned short)(u.z >> 16));
  s += b2f((unsigned short)(u.w & 0xffff));
  s += b2f((unsigned short)(u.w >> 16));
  red[threadIdx.x] = s;
  __syncthreads();
  for (int st = 128; st > 0; st >>= 1) {
    if (threadIdx.x < st) red[threadIdx.x] += red[threadIdx.x + st];
    __syncthreads();
  }
  if (threadIdx.x == 0) vsum[blockIdx.x] = red[0];
}

// ---------------------------------------------------------------- flash attention v3
// Balanced zigzag q-tiles + XCD swizzle + double-buffered LDS staging (GLD16,
// pre-swizzled source) + XOR-swizzled ds_read_b128 fragments. QBLK=64, 16 rows/wave.
__global__ __launch_bounds__(256) void flash_attn3(const unsigned short* __restrict__ Q,
                                                   const unsigned short* __restrict__ Kp,
                                                   const unsigned short* __restrict__ Vt,
                                                   const int* __restrict__ mask,
                                                   const int* __restrict__ fu,
                                                   const float* __restrict__ vsum,
                                                   float* __restrict__ O) {
  const int S = 2048, DM = 1024;
  const int bid = blockIdx.x;                       // 0..1023
  const int wid = ((bid & 7) << 7) | (bid >> 3);    // XCD swizzle: same-XCD -> contiguous wids
  const int zz = wid & 31, bh = wid >> 5;
  const int qt = (zz & 1) ? (31 - (zz >> 1)) : (zz >> 1);  // zigzag balance
  const int b = bh >> 4, h = bh & 15;
  const int tid = threadIdx.x, lane = tid & 63, wave = tid >> 6;
  const int row16 = lane & 15, kgrp = lane >> 4;

  __shared__ unsigned short Ks[2][64][64];   // 16 KB
  __shared__ unsigned short Vs[2][64][64];   // 16 KB (V^T tile: rows=d, cols=k)
  __shared__ unsigned short Ps[4][16][72];   // per-wave P round-trip

  const int q0 = qt * 64 + wave * 16;
  const size_t base = ((size_t)b * S) * DM + h * 64;
  const size_t vtb = ((size_t)(b * 1024 + h * 64)) * S;

  // staging geometry: lane l writes LDS row (chunk*8 + (l>>3)), 16B slot (l&7).
  // pre-swizzle the SOURCE so LDS[row][slot] = glob[row][slot ^ (row&7)].
  const int srow = lane >> 3;
  const int sslot = (lane & 7) ^ srow;

  s16x8 qf[2];
#pragma unroll
  for (int kk = 0; kk < 2; kk++)
    qf[kk] = *(const s16x8*)&Q[base + (size_t)(q0 + row16) * DM + kk * 32 + kgrp * 8];

  f32x4 oacc[4] = {};
  float m_run[4], l_run[4];
#pragma unroll
  for (int r = 0; r < 4; r++) { m_run[r] = -1e30f; l_run[r] = 0.f; }

  const int* maskb = mask + b * S;
  const int nt = qt + 1;

  auto stage = [&](int t, int bf) {
    const int kb = t * 64;
#pragma unroll
    for (int c2 = 0; c2 < 2; c2++) {
      const int r = wave * 16 + c2 * 8 + srow;
      GLD16(Kp + base + (size_t)(kb + r) * DM + sslot * 8,
            (char*)&Ks[bf][0][0] + (wave * 2 + c2) * 1024);
      GLD16(Vt + vtb + (size_t)r * S + kb + sslot * 8,
            (char*)&Vs[bf][0][0] + (wave * 2 + c2) * 1024);
    }
  };

  stage(0, 0);
  asm volatile("s_waitcnt vmcnt(0)" ::: "memory");
  __syncthreads();

  int cur = 0;
  for (int t = 0; t < nt; ++t) {
    if (t + 1 < nt) stage(t + 1, cur ^ 1);   // prefetch next tile into other buffer
    const int kb = t * 64;

    // QK^T from swizzled LDS
    f32x4 sc[4];
#pragma unroll
    for (int nf = 0; nf < 4; nf++) {
      const int rr = nf * 16 + row16, sw = row16 & 7;
      s16x8 k0 = *(const s16x8*)&Ks[cur][rr][(kgrp ^ sw) * 8];
      s16x8 k1 = *(const s16x8*)&Ks[cur][rr][((4 + kgrp) ^ sw) * 8];
      f32x4 a = {};
      a = MFMA16(qf[0], k0, a);
      a = MFMA16(qf[1], k1, a);
      sc[nf] = a;
    }

    // scale + pad mask + causal (exact NEG = -10000 semantics)
    int mv[4];
#pragma unroll
    for (int nf = 0; nf < 4; nf++) mv[nf] = maskb[kb + nf * 16 + row16];
#pragma unroll
    for (int nf = 0; nf < 4; nf++) {
      int kg = kb + nf * 16 + row16;
#pragma unroll
      for (int r = 0; r < 4; r++) {
        int qg = q0 + kgrp * 4 + r;
        float s = sc[nf][r] * 0.125f;
        sc[nf][r] = (kg > qg || mv[nf] == 0) ? -10000.0f : s;
      }
    }

    // online softmax
    float tmax[4];
#pragma unroll
    for (int r = 0; r < 4; r++)
      tmax[r] = fmaxf(fmaxf(sc[0][r], sc[1][r]), fmaxf(sc[2][r], sc[3][r]));
#pragma unroll
    for (int d = 1; d < 16; d <<= 1)
#pragma unroll
      for (int r = 0; r < 4; r++) tmax[r] = fmaxf(tmax[r], __shfl_xor(tmax[r], d));

    float mnew[4], alpha[4], rsum[4];
#pragma unroll
    for (int r = 0; r < 4; r++) {
      mnew[r] = fmaxf(m_run[r], tmax[r]);
      alpha[r] = __expf(m_run[r] - mnew[r]);
      m_run[r] = mnew[r];
      rsum[r] = 0.f;
    }
#pragma unroll
    for (int nf = 0; nf < 4; nf++)
#pragma unroll
      for (int r = 0; r < 4; r++) {
        float p = __expf(sc[nf][r] - mnew[r]);
        sc[nf][r] = p;
        rsum[r] += p;
      }
#pragma unroll
    for (int d = 1; d < 16; d <<= 1)
#pragma unroll
      for (int r = 0; r < 4; r++) rsum[r] += __shfl_xor(rsum[r], d);
#pragma unroll
    for (int r = 0; r < 4; r++) l_run[r] = l_run[r] * alpha[r] + rsum[r];
#pragma unroll
    for (int nf = 0; nf < 4; nf++)
#pragma unroll
      for (int r = 0; r < 4; r++) oacc[nf][r] *= alpha[r];

    // P -> per-wave LDS (bf16), reload as A-fragments (wave-local, no barrier)
#pragma unroll
    for (int nf = 0; nf < 4; nf++)
#pragma unroll
      for (int r = 0; r < 4; r++)
        Ps[wave][kgrp * 4 + r][nf * 16 + row16] = f2bu(sc[nf][r]);

    s16x8 pf0 = *(const s16x8*)&Ps[wave][row16][kgrp * 8];
    s16x8 pf1 = *(const s16x8*)&Ps[wave][row16][32 + kgrp * 8];

    // PV from swizzled V^T LDS
#pragma unroll
    for (int nf2 = 0; nf2 < 4; nf2++) {
      const int rr = nf2 * 16 + row16, sw = row16 & 7;
      s16x8 v0 = *(const s16x8*)&Vs[cur][rr][(kgrp ^ sw) * 8];
      s16x8 v1 = *(const s16x8*)&Vs[cur][rr][((4 + kgrp) ^ sw) * 8];
      oacc[nf2] = MFMA16(pf0, v0, oacc[nf2]);
      oacc[nf2] = MFMA16(pf1, v1, oacc[nf2]);
    }

    asm volatile("s_waitcnt vmcnt(0)" ::: "memory");  // next-tile stage landed
    __syncthreads();
    cur ^= 1;
  }

  // epilogue: normalize; rows before first unmasked key get uniform mean over ALL 2048 V rows
  const int fub = fu[b];
  const float* vs = vsum + b * DM + h * 64;
#pragma unroll
  for (int nf2 = 0; nf2 < 4; nf2++)
#pragma unroll
    for (int r = 0; r < 4; r++) {
      int qg = q0 + kgrp * 4 + r;
      int d = nf2 * 16 + row16;
      float val = oacc[nf2][r] / l_run[r];
      if (qg < fub) val = vs[d] * (1.0f / 2048.0f);
      O[base + (size_t)qg * DM + d] = val;
    }
}

// ---------------------------------------------------------------- launch
extern "C" void kernel_launch(void* const* d_in, const int* in_sizes, int n_in,
                              void* d_out, int out_size, void* d_ws, size_t ws_size,
                              hipStream_t stream) {
  const float* q    = (const float*)d_in[0];
  const float* k    = (const float*)d_in[1];
  const float* v    = (const float*)d_in[2];
  const int*   mask = (const int*)d_in[3];
  const float* Wq   = (const float*)d_in[4];
  const float* Wk   = (const float*)d_in[5];
  const float* Wv   = (const float*)d_in[6];
  const float* Wo   = (const float*)d_in[7];
  float* out = (float*)d_out;
  char* ws = (char*)d_ws;

  unsigned short* Wqb = (unsigned short*)(ws + (size_t)0);
  unsigned short* Wkb = (unsigned short*)(ws + ((size_t)2 << 20));
  unsigned short* Wvb = (unsigned short*)(ws + ((size_t)4 << 20));
  unsigned short* Wob = (unsigned short*)(ws + ((size_t)6 << 20));
  unsigned short* Qb  = (unsigned short*)(ws + ((size_t)8 << 20));
  unsigned short* Kb  = (unsigned short*)(ws + ((size_t)16 << 20));
  unsigned short* Vt  = (unsigned short*)(ws + ((size_t)24 << 20));
  float* attn = (float*)(ws + ((size_t)32 << 20));
  float* vsum = (float*)(ws + ((size_t)48 << 20));
  int*   fub  = (int*)(ws + ((size_t)48 << 20) + (64 << 10));

  cast_w4<<<dim3(1024, 4), 256, 0, stream>>>(Wq, Wk, Wv, Wo, Wqb, Wkb, Wvb, Wob);

  qkv_gemm<<<dim3(8, 32, 3), 256, 0, stream>>>(q, k, v, Wqb, Wkb, Wvb, Qb, Kb, Vt);

  fu_kernel<<<2, 256, 0, stream>>>(mask, fub);
  reduce_vt<<<2048, 256, 0, stream>>>(Vt, vsum);

  flash_attn3<<<1024, 256, 0, stream>>>(Qb, Kb, Vt, mask, fub, vsum, attn);

  gemm_wo<<<dim3(8, 32), 256, 0, stream>>>(attn, Wob, out);
}

// Round 4
// 188.395 us; speedup vs baseline: 1.6773x; 1.2878x over previous
//
#include <hip/hip_runtime.h>
#include <hip/hip_bf16.h>

typedef __attribute__((ext_vector_type(8))) short s16x8;
typedef __attribute__((ext_vector_type(4))) float f32x4;

#define MFMA16(a,b,c) __builtin_amdgcn_mfma_f32_16x16x32_bf16((a),(b),(c),0,0,0)

#define GLD16(gp, lp) __builtin_amdgcn_global_load_lds( \
  (const __attribute__((address_space(1))) unsigned int*)(gp), \
  (__attribute__((address_space(3))) unsigned int*)(lp), 16, 0, 0)

static __device__ __forceinline__ unsigned short f2bu(float f) {
  __hip_bfloat16 h = __float2bfloat16(f);
  unsigned short u; __builtin_memcpy(&u, &h, 2); return u;
}
static __device__ __forceinline__ float b2f(unsigned short u) {
  unsigned int x = ((unsigned int)u) << 16; float f; __builtin_memcpy(&f, &x, 4); return f;
}

// ---------------------------------------------------------------- cast all 4 weights, one launch
__global__ __launch_bounds__(256) void cast_w4(const float* __restrict__ w0, const float* __restrict__ w1,
                                               const float* __restrict__ w2, const float* __restrict__ w3,
                                               unsigned short* __restrict__ o0, unsigned short* __restrict__ o1,
                                               unsigned short* __restrict__ o2, unsigned short* __restrict__ o3) {
  const int y = blockIdx.y;
  const float* in = (y == 0) ? w0 : (y == 1) ? w1 : (y == 2) ? w2 : w3;
  unsigned short* out = (y == 0) ? o0 : (y == 1) ? o1 : (y == 2) ? o2 : o3;
  int i = blockIdx.x * 256 + threadIdx.x;   // 0..262143 float4s
  float4 v = *(const float4*)(in + (size_t)i * 4);
  unsigned int p0 = (unsigned int)f2bu(v.x) | ((unsigned int)f2bu(v.y) << 16);
  unsigned int p1 = (unsigned int)f2bu(v.z) | ((unsigned int)f2bu(v.w) << 16);
  uint2 pk; pk.x = p0; pk.y = p1;
  *(uint2*)(out + (size_t)i * 4) = pk;
}

// ---------------------------------------------------------------- shared GEMM core: C = A(f32) * Bw(bf16)^T
static __device__ __forceinline__ void gemm_core(const float* __restrict__ A,
                                                 const unsigned short* __restrict__ Bw,
                                                 int m0, int n0,
                                                 f32x4 (&acc)[4][4],
                                                 unsigned short (*As)[64], unsigned short (*Bs)[64]) {
  const int K = 1024;
  const int tid = threadIdx.x;
  const int lane = tid & 63, wave = tid >> 6;
  const int wm = wave >> 1, wn = wave & 1;
  const int row16 = lane & 15, kgrp = lane >> 4;

  for (int k0 = 0; k0 < K; k0 += 64) {
#pragma unroll
    for (int i = 0; i < 4; i++) {
      int rr = (wave * 4 + i) * 8 + (lane >> 3);
      const unsigned short* gp = Bw + (size_t)(n0 + rr) * K + k0 + (lane & 7) * 8;
      GLD16(gp, (char*)Bs + (wave * 4 + i) * 1024);
    }
    const float* Ag = A + (size_t)m0 * K + k0;
#pragma unroll
    for (int i = 0; i < 8; i++) {
      int f = tid + i * 256;
      int r = f >> 4, c4 = (f & 15) * 4;
      float4 v = *(const float4*)(Ag + (size_t)r * K + c4);
      unsigned int p0 = (unsigned int)f2bu(v.x) | ((unsigned int)f2bu(v.y) << 16);
      unsigned int p1 = (unsigned int)f2bu(v.z) | ((unsigned int)f2bu(v.w) << 16);
      uint2 pk; pk.x = p0; pk.y = p1;
      *(uint2*)&As[r][c4] = pk;
    }
    __syncthreads();

#pragma unroll
    for (int kk = 0; kk < 2; kk++) {
      s16x8 af[4], bfr[4];
#pragma unroll
      for (int mi = 0; mi < 4; mi++)
        af[mi] = *(const s16x8*)&As[wm * 64 + mi * 16 + row16][kk * 32 + kgrp * 8];
#pragma unroll
      for (int ni = 0; ni < 4; ni++)
        bfr[ni] = *(const s16x8*)&Bs[wn * 64 + ni * 16 + row16][kk * 32 + kgrp * 8];
#pragma unroll
      for (int mi = 0; mi < 4; mi++)
#pragma unroll
        for (int ni = 0; ni < 4; ni++)
          acc[mi][ni] = MFMA16(af[mi], bfr[ni], acc[mi][ni]);
    }
    __syncthreads();
  }
}

// fused Q/K/V projection; z=0 -> Qb linear, z=1 -> Kb linear, z=2 -> Vt transposed [b*1024+n][2048]
__global__ __launch_bounds__(256) void qkv_gemm(const float* __restrict__ q, const float* __restrict__ k,
                                                const float* __restrict__ v,
                                                const unsigned short* __restrict__ Wqb,
                                                const unsigned short* __restrict__ Wkb,
                                                const unsigned short* __restrict__ Wvb,
                                                unsigned short* __restrict__ Qb,
                                                unsigned short* __restrict__ Kb,
                                                unsigned short* __restrict__ Vt) {
  __shared__ unsigned short As[128][64];
  __shared__ unsigned short Bs[128][64];
  const int z = blockIdx.z;
  const float* A = (z == 0) ? q : (z == 1) ? k : v;
  const unsigned short* Bw = (z == 0) ? Wqb : (z == 1) ? Wkb : Wvb;
  const int m0 = blockIdx.y * 128, n0 = blockIdx.x * 128;

  f32x4 acc[4][4] = {};
  gemm_core(A, Bw, m0, n0, acc, As, Bs);

  const int lane = threadIdx.x & 63, wave = threadIdx.x >> 6;
  const int wm = wave >> 1, wn = wave & 1;
  const int row16 = lane & 15, kgrp = lane >> 4;

  if (z < 2) {
    unsigned short* C = z ? Kb : Qb;
#pragma unroll
    for (int mi = 0; mi < 4; mi++)
#pragma unroll
      for (int ni = 0; ni < 4; ni++)
#pragma unroll
        for (int r = 0; r < 4; r++) {
          int row = m0 + wm * 64 + mi * 16 + kgrp * 4 + r;
          int col = n0 + wn * 64 + ni * 16 + row16;
          C[(size_t)row * 1024 + col] = f2bu(acc[mi][ni][r]);
        }
  } else {
#pragma unroll
    for (int mi = 0; mi < 4; mi++)
#pragma unroll
      for (int ni = 0; ni < 4; ni++) {
        int mb = m0 + wm * 64 + mi * 16 + kgrp * 4;
        int col = n0 + wn * 64 + ni * 16 + row16;
        int bb = mb >> 11, s = mb & 2047;
        unsigned int p0 = (unsigned int)f2bu(acc[mi][ni][0]) | ((unsigned int)f2bu(acc[mi][ni][1]) << 16);
        unsigned int p1 = (unsigned int)f2bu(acc[mi][ni][2]) | ((unsigned int)f2bu(acc[mi][ni][3]) << 16);
        uint2 pk; pk.x = p0; pk.y = p1;
        *(uint2*)&Vt[(((size_t)(bb * 1024 + col)) << 11) + s] = pk;
      }
  }
}

// output projection: out = attn(f32) * Wo(bf16)^T, f32 out
__global__ __launch_bounds__(256) void gemm_wo(const float* __restrict__ A,
                                               const unsigned short* __restrict__ Bw,
                                               float* __restrict__ C) {
  __shared__ unsigned short As[128][64];
  __shared__ unsigned short Bs[128][64];
  const int m0 = blockIdx.y * 128, n0 = blockIdx.x * 128;
  f32x4 acc[4][4] = {};
  gemm_core(A, Bw, m0, n0, acc, As, Bs);

  const int lane = threadIdx.x & 63, wave = threadIdx.x >> 6;
  const int wm = wave >> 1, wn = wave & 1;
  const int row16 = lane & 15, kgrp = lane >> 4;
#pragma unroll
  for (int mi = 0; mi < 4; mi++)
#pragma unroll
    for (int ni = 0; ni < 4; ni++)
#pragma unroll
      for (int r = 0; r < 4; r++) {
        int row = m0 + wm * 64 + mi * 16 + kgrp * 4 + r;
        int col = n0 + wn * 64 + ni * 16 + row16;
        C[(size_t)row * 1024 + col] = acc[mi][ni][r];
      }
}

// ---------------------------------------------------------------- first unmasked key per batch
__global__ __launch_bounds__(256) void fu_kernel(const int* __restrict__ mask, int* __restrict__ fu) {
  const int S = 2048;
  int b = blockIdx.x;
  __shared__ int red[256];
  int best = S;
  for (int k = threadIdx.x; k < S; k += 256)
    if (mask[b * S + k] != 0 && k < best) best = k;
  red[threadIdx.x] = best;
  __syncthreads();
  for (int s = 128; s > 0; s >>= 1) {
    if (threadIdx.x < s) red[threadIdx.x] = min(red[threadIdx.x], red[threadIdx.x + s]);
    __syncthreads();
  }
  if (threadIdx.x == 0) fu[b] = red[0];
}

// ---------------------------------------------------------------- V column sums from Vt (deterministic)
__global__ __launch_bounds__(256) void reduce_vt(const unsigned short* __restrict__ Vt,
                                                 float* __restrict__ vsum) {
  __shared__ float red[256];
  const unsigned short* p = Vt + ((size_t)blockIdx.x << 11) + threadIdx.x * 8;
  uint4 u = *(const uint4*)p;
  float s = b2f((unsigned short)(u.x & 0xffff));
  s += b2f((unsigned short)(u.x >> 16));
  s += b2f((unsigned short)(u.y & 0xffff));
  s += b2f((unsigned short)(u.y >> 16));
  s += b2f((unsigned short)(u.z & 0xffff));
  s += b2f((unsigned short)(u.z >> 16));
  s += b2f((unsigned short)(u.w & 0xffff));
  s += b2f((unsigned short)(u.w >> 16));
  red[threadIdx.x] = s;
  __syncthreads();
  for (int st = 128; st > 0; st >>= 1) {
    if (threadIdx.x < st) red[threadIdx.x] += red[threadIdx.x + st];
    __syncthreads();
  }
  if (threadIdx.x == 0) vsum[blockIdx.x] = red[0];
}

// ---------------------------------------------------------------- flash attention v4
// Swapped QK^T (S^T = mfma(K,Q)) so q is lane-local: in-lane softmax + 2 shfl.
// PV as O^T = mfma(V^T, P^T). 512 blocks, each owns q-tile pair (qt, 31-qt) = 33 k-tiles.
__global__ __launch_bounds__(256) void flash_attn4(const unsigned short* __restrict__ Q,
                                                   const unsigned short* __restrict__ Kp,
                                                   const unsigned short* __restrict__ Vt,
                                                   const int* __restrict__ mask,
                                                   const int* __restrict__ fu,
                                                   const float* __restrict__ vsum,
                                                   float* __restrict__ O) {
  const int S = 2048, DM = 1024;
  const int xcd = blockIdx.x & 7, idx = blockIdx.x >> 3;   // 64 blocks per XCD
  const int bh = xcd * 4 + (idx >> 4);                     // 4 (b,h) per XCD -> ~3MB L2 set
  const int pairq = idx & 15;
  const int b = bh >> 4, h = bh & 15;
  const int tid = threadIdx.x, lane = tid & 63, wave = tid >> 6;
  const int row16 = lane & 15, kgrp = lane >> 4;

  __shared__ unsigned short Ks[2][64][64];   // 16 KB, XOR-swizzled 8B slots
  __shared__ unsigned short Vs[2][64][64];   // 16 KB (V^T tile: rows=d, cols=k), swizzled
  __shared__ unsigned short Ps[4][16][72];   // per-wave P [q][k], padded rows

  const size_t base = ((size_t)b * S) * DM + h * 64;
  const size_t vtb = ((size_t)(b * 1024 + h * 64)) * S;
  const int* maskb = mask + b * S;

  const int srow = lane >> 3;
  const int sslot = (lane & 7) ^ srow;

  const int fub = fu[b];
  const float* vs = vsum + b * DM + h * 64;
  const int sw = row16 & 7;

#pragma unroll
  for (int pass = 0; pass < 2; ++pass) {
    const int qt = pass ? (31 - pairq) : pairq;
    const int q0 = qt * 64 + wave * 16;
    const int qg = q0 + row16;                 // this lane's q row (lane-local!)
    const int nt = qt + 1;

    s16x8 qf0 = *(const s16x8*)&Q[base + (size_t)qg * DM + kgrp * 8];
    s16x8 qf1 = *(const s16x8*)&Q[base + (size_t)qg * DM + 32 + kgrp * 8];

    f32x4 oacc[4] = {};
    float m_run = -1e30f, l_run = 0.f;

    auto stage = [&](int t, int bf) {
      const int kb = t * 64;
#pragma unroll
      for (int c2 = 0; c2 < 2; c2++) {
        const int r = wave * 16 + c2 * 8 + srow;
        GLD16(Kp + base + (size_t)(kb + r) * DM + sslot * 8,
              (char*)&Ks[bf][0][0] + (wave * 2 + c2) * 1024);
        GLD16(Vt + vtb + (size_t)r * S + kb + sslot * 8,
              (char*)&Vs[bf][0][0] + (wave * 2 + c2) * 1024);
      }
    };

    stage(0, 0);
    asm volatile("s_waitcnt vmcnt(0)" ::: "memory");
    __syncthreads();

    int cur = 0;
    for (int t = 0; t < nt; ++t) {
      if (t + 1 < nt) stage(t + 1, cur ^ 1);
      const int kb = t * 64;

      // S^T = K * Q^T : lane holds scores for q=qg, k = kb + nf*16 + kgrp*4 + r
      f32x4 sc[4];
#pragma unroll
      for (int nf = 0; nf < 4; nf++) {
        const int rr = nf * 16 + row16;
        s16x8 k0 = *(const s16x8*)&Ks[cur][rr][(kgrp ^ sw) * 8];
        s16x8 k1 = *(const s16x8*)&Ks[cur][rr][((4 + kgrp) ^ sw) * 8];
        f32x4 a = {};
        a = MFMA16(k0, qf0, a);
        a = MFMA16(k1, qf1, a);
        sc[nf] = a;
      }

      // scale + pad mask + causal (exact NEG = -10000 semantics)
#pragma unroll
      for (int nf = 0; nf < 4; nf++) {
        const int kbase = kb + nf * 16 + kgrp * 4;
        int4 mv = *(const int4*)&maskb[kbase];
#pragma unroll
        for (int r = 0; r < 4; r++) {
          int m_ok = (r == 0) ? mv.x : (r == 1) ? mv.y : (r == 2) ? mv.z : mv.w;
          float s = sc[nf][r] * 0.125f;
          sc[nf][r] = (kbase + r > qg || m_ok == 0) ? -10000.0f : s;
        }
      }

      // softmax: in-lane over 16, then 2 shfl over the 4 lanes sharing this q
      float t01 = fmaxf(fmaxf(sc[0][0], sc[0][1]), fmaxf(sc[0][2], sc[0][3]));
      float t23 = fmaxf(fmaxf(sc[1][0], sc[1][1]), fmaxf(sc[1][2], sc[1][3]));
      float t45 = fmaxf(fmaxf(sc[2][0], sc[2][1]), fmaxf(sc[2][2], sc[2][3]));
      float t67 = fmaxf(fmaxf(sc[3][0], sc[3][1]), fmaxf(sc[3][2], sc[3][3]));
      float tmax = fmaxf(fmaxf(t01, t23), fmaxf(t45, t67));
      tmax = fmaxf(tmax, __shfl_xor(tmax, 16));
      tmax = fmaxf(tmax, __shfl_xor(tmax, 32));

      float mnew = fmaxf(m_run, tmax);
      float alpha = __expf(m_run - mnew);
      m_run = mnew;

      float rsum = 0.f;
#pragma unroll
      for (int nf = 0; nf < 4; nf++)
#pragma unroll
        for (int r = 0; r < 4; r++) {
          float p = __expf(sc[nf][r] - mnew);
          sc[nf][r] = p;
          rsum += p;
        }
      rsum += __shfl_xor(rsum, 16);
      rsum += __shfl_xor(rsum, 32);
      l_run = l_run * alpha + rsum;
#pragma unroll
      for (int nf2 = 0; nf2 < 4; nf2++)
#pragma unroll
        for (int r = 0; r < 4; r++) oacc[nf2][r] *= alpha;

      // P pack: 4 consecutive k per nf -> one 8B write each
#pragma unroll
      for (int nf = 0; nf < 4; nf++) {
        uint2 pk;
        pk.x = (unsigned int)f2bu(sc[nf][0]) | ((unsigned int)f2bu(sc[nf][1]) << 16);
        pk.y = (unsigned int)f2bu(sc[nf][2]) | ((unsigned int)f2bu(sc[nf][3]) << 16);
        *(uint2*)&Ps[wave][row16][nf * 16 + kgrp * 4] = pk;
      }
      // B-frag of P^T: lane holds P[q=row16][k=kk*32+kgrp*8+j] (wave-local, no barrier)
      s16x8 pf0 = *(const s16x8*)&Ps[wave][row16][kgrp * 8];
      s16x8 pf1 = *(const s16x8*)&Ps[wave][row16][32 + kgrp * 8];

      // O^T += V^T * P^T
#pragma unroll
      for (int nf2 = 0; nf2 < 4; nf2++) {
        const int rr = nf2 * 16 + row16;
        s16x8 v0 = *(const s16x8*)&Vs[cur][rr][(kgrp ^ sw) * 8];
        s16x8 v1 = *(const s16x8*)&Vs[cur][rr][((4 + kgrp) ^ sw) * 8];
        oacc[nf2] = MFMA16(v0, pf0, oacc[nf2]);
        oacc[nf2] = MFMA16(v1, pf1, oacc[nf2]);
      }

      asm volatile("s_waitcnt vmcnt(0)" ::: "memory");
      __syncthreads();
      cur ^= 1;
    }

    // epilogue: lane owns q=qg, d = nf2*16 + kgrp*4 + r -> float4 stores
    const float rl = 1.0f / l_run;
#pragma unroll
    for (int nf2 = 0; nf2 < 4; nf2++) {
      const int d0 = nf2 * 16 + kgrp * 4;
      float4 val;
      val.x = oacc[nf2][0] * rl;
      val.y = oacc[nf2][1] * rl;
      val.z = oacc[nf2][2] * rl;
      val.w = oacc[nf2][3] * rl;
      if (qg < fub) {
        float4 vv = *(const float4*)&vs[d0];
        val.x = vv.x * (1.0f / 2048.0f);
        val.y = vv.y * (1.0f / 2048.0f);
        val.z = vv.z * (1.0f / 2048.0f);
        val.w = vv.w * (1.0f / 2048.0f);
      }
      *(float4*)&O[base + (size_t)qg * DM + d0] = val;
    }
  }
}

// ---------------------------------------------------------------- launch
extern "C" void kernel_launch(void* const* d_in, const int* in_sizes, int n_in,
                              void* d_out, int out_size, void* d_ws, size_t ws_size,
                              hipStream_t stream) {
  const float* q    = (const float*)d_in[0];
  const float* k    = (const float*)d_in[1];
  const float* v    = (const float*)d_in[2];
  const int*   mask = (const int*)d_in[3];
  const float* Wq   = (const float*)d_in[4];
  const float* Wk   = (const float*)d_in[5];
  const float* Wv   = (const float*)d_in[6];
  const float* Wo   = (const float*)d_in[7];
  float* out = (float*)d_out;
  char* ws = (char*)d_ws;

  unsigned short* Wqb = (unsigned short*)(ws + (size_t)0);
  unsigned short* Wkb = (unsigned short*)(ws + ((size_t)2 << 20));
  unsigned short* Wvb = (unsigned short*)(ws + ((size_t)4 << 20));
  unsigned short* Wob = (unsigned short*)(ws + ((size_t)6 << 20));
  unsigned short* Qb  = (unsigned short*)(ws + ((size_t)8 << 20));
  unsigned short* Kb  = (unsigned short*)(ws + ((size_t)16 << 20));
  unsigned short* Vt  = (unsigned short*)(ws + ((size_t)24 << 20));
  float* attn = (float*)(ws + ((size_t)32 << 20));
  float* vsum = (float*)(ws + ((size_t)48 << 20));
  int*   fub  = (int*)(ws + ((size_t)48 << 20) + (64 << 10));

  cast_w4<<<dim3(1024, 4), 256, 0, stream>>>(Wq, Wk, Wv, Wo, Wqb, Wkb, Wvb, Wob);

  qkv_gemm<<<dim3(8, 32, 3), 256, 0, stream>>>(q, k, v, Wqb, Wkb, Wvb, Qb, Kb, Vt);

  fu_kernel<<<2, 256, 0, stream>>>(mask, fub);
  reduce_vt<<<2048, 256, 0, stream>>>(Vt, vsum);

  flash_attn4<<<512, 256, 0, stream>>>(Qb, Kb, Vt, mask, fub, vsum, attn);

  gemm_wo<<<dim3(8, 32), 256, 0, stream>>>(attn, Wob, out);
}

// Round 5
// 159.374 us; speedup vs baseline: 1.9828x; 1.1821x over previous
//
#include <hip/hip_runtime.h>
#include <hip/hip_bf16.h>

typedef __attribute__((ext_vector_type(8))) short s16x8;
typedef __attribute__((ext_vector_type(4))) float f32x4;

#define MFMA16(a,b,c) __builtin_amdgcn_mfma_f32_16x16x32_bf16((a),(b),(c),0,0,0)

#define GLD16(gp, lp) __builtin_amdgcn_global_load_lds( \
  (const __attribute__((address_space(1))) unsigned int*)(gp), \
  (__attribute__((address_space(3))) unsigned int*)(lp), 16, 0, 0)

static __device__ __forceinline__ unsigned short f2bu(float f) {
  __hip_bfloat16 h = __float2bfloat16(f);
  unsigned short u; __builtin_memcpy(&u, &h, 2); return u;
}
static __device__ __forceinline__ float b2f(unsigned short u) {
  unsigned int x = ((unsigned int)u) << 16; float f; __builtin_memcpy(&f, &x, 4); return f;
}

// ---------------------------------------------------------------- cast all 4 weights, one launch
__global__ __launch_bounds__(256) void cast_w4(const float* __restrict__ w0, const float* __restrict__ w1,
                                               const float* __restrict__ w2, const float* __restrict__ w3,
                                               unsigned short* __restrict__ o0, unsigned short* __restrict__ o1,
                                               unsigned short* __restrict__ o2, unsigned short* __restrict__ o3) {
  const int y = blockIdx.y;
  const float* in = (y == 0) ? w0 : (y == 1) ? w1 : (y == 2) ? w2 : w3;
  unsigned short* out = (y == 0) ? o0 : (y == 1) ? o1 : (y == 2) ? o2 : o3;
  int i = blockIdx.x * 256 + threadIdx.x;   // 0..262143 float4s
  float4 v = *(const float4*)(in + (size_t)i * 4);
  unsigned int p0 = (unsigned int)f2bu(v.x) | ((unsigned int)f2bu(v.y) << 16);
  unsigned int p1 = (unsigned int)f2bu(v.z) | ((unsigned int)f2bu(v.w) << 16);
  uint2 pk; pk.x = p0; pk.y = p1;
  *(uint2*)(out + (size_t)i * 4) = pk;
}

// ---------------------------------------------------------------- shared GEMM core: C = A(f32) * Bw(bf16)^T
// XOR-swizzled LDS: 16B slot s of row r lives at physical slot s^(r&7).
// B staged via GLD16 with pre-swizzled SOURCE; A staged reg->swizzled ds_write.
static __device__ __forceinline__ void gemm_core(const float* __restrict__ A,
                                                 const unsigned short* __restrict__ Bw,
                                                 int m0, int n0,
                                                 f32x4 (&acc)[4][4],
                                                 unsigned short (*As)[64], unsigned short (*Bs)[64]) {
  const int K = 1024;
  const int tid = threadIdx.x;
  const int lane = tid & 63, wave = tid >> 6;
  const int wm = wave >> 1, wn = wave & 1;
  const int row16 = lane & 15, kgrp = lane >> 4;
  const int srow = lane >> 3, sslot = (lane & 7) ^ srow;
  const int sw = row16 & 7;

  for (int k0 = 0; k0 < K; k0 += 64) {
    // B: async global->LDS, source column pre-swizzled
#pragma unroll
    for (int i = 0; i < 4; i++) {
      int rr = (wave * 4 + i) * 8 + srow;
      GLD16(Bw + (size_t)(n0 + rr) * K + k0 + sslot * 8,
            (char*)Bs + (wave * 4 + i) * 1024);
    }
    // A: f32 load, convert, swizzled 8B ds_write
    const float* Ag = A + (size_t)m0 * K + k0;
#pragma unroll
    for (int i = 0; i < 8; i++) {
      int f = tid + i * 256;
      int r = f >> 4, c = f & 15;            // c = 8B half-slot 0..15
      float4 v = *(const float4*)(Ag + (size_t)r * K + c * 4);
      unsigned int p0 = (unsigned int)f2bu(v.x) | ((unsigned int)f2bu(v.y) << 16);
      unsigned int p1 = (unsigned int)f2bu(v.z) | ((unsigned int)f2bu(v.w) << 16);
      uint2 pk; pk.x = p0; pk.y = p1;
      int slot = (c >> 1) ^ (r & 7), half = c & 1;
      *(uint2*)((char*)&As[r][0] + slot * 16 + half * 8) = pk;
    }
    __syncthreads();

#pragma unroll
    for (int kk = 0; kk < 2; kk++) {
      s16x8 af[4], bfr[4];
#pragma unroll
      for (int mi = 0; mi < 4; mi++) {
        int rr = wm * 64 + mi * 16 + row16;
        af[mi] = *(const s16x8*)((char*)&As[rr][0] + ((kk * 4 + kgrp) ^ sw) * 16);
      }
#pragma unroll
      for (int ni = 0; ni < 4; ni++) {
        int rr = wn * 64 + ni * 16 + row16;
        bfr[ni] = *(const s16x8*)((char*)&Bs[rr][0] + ((kk * 4 + kgrp) ^ sw) * 16);
      }
#pragma unroll
      for (int mi = 0; mi < 4; mi++)
#pragma unroll
        for (int ni = 0; ni < 4; ni++)
          acc[mi][ni] = MFMA16(af[mi], bfr[ni], acc[mi][ni]);
    }
    __syncthreads();
  }
}

// fused Q/K/V projection, 1D grid 768, XCD-aware: unit g=(z,mstrip) lives on one XCD
// with its 8 n-blocks co-resident (A strip L2-resident). z=2 writes Vt transposed.
__global__ __launch_bounds__(256) void qkv_gemm(const float* __restrict__ q, const float* __restrict__ k,
                                                const float* __restrict__ v,
                                                const unsigned short* __restrict__ Wqb,
                                                const unsigned short* __restrict__ Wkb,
                                                const unsigned short* __restrict__ Wvb,
                                                unsigned short* __restrict__ Qb,
                                                unsigned short* __restrict__ Kb,
                                                unsigned short* __restrict__ Vt) {
  __shared__ unsigned short As[128][64];
  __shared__ unsigned short Bs[128][64];
  const int xcd = blockIdx.x & 7, u = blockIdx.x >> 3;   // u 0..95
  const int g = xcd * 12 + (u >> 3);                     // unit 0..95
  const int z = g >> 5, mstrip = g & 31;
  const int m0 = mstrip * 128, n0 = (u & 7) * 128;

  const float* A = (z == 0) ? q : (z == 1) ? k : v;
  const unsigned short* Bw = (z == 0) ? Wqb : (z == 1) ? Wkb : Wvb;

  f32x4 acc[4][4] = {};
  gemm_core(A, Bw, m0, n0, acc, As, Bs);

  const int lane = threadIdx.x & 63, wave = threadIdx.x >> 6;
  const int wm = wave >> 1, wn = wave & 1;
  const int row16 = lane & 15, kgrp = lane >> 4;

  if (z < 2) {
    unsigned short* C = z ? Kb : Qb;
#pragma unroll
    for (int mi = 0; mi < 4; mi++)
#pragma unroll
      for (int ni = 0; ni < 4; ni++)
#pragma unroll
        for (int r = 0; r < 4; r++) {
          int row = m0 + wm * 64 + mi * 16 + kgrp * 4 + r;
          int col = n0 + wn * 64 + ni * 16 + row16;
          C[(size_t)row * 1024 + col] = f2bu(acc[mi][ni][r]);
        }
  } else {
#pragma unroll
    for (int mi = 0; mi < 4; mi++)
#pragma unroll
      for (int ni = 0; ni < 4; ni++) {
        int mb = m0 + wm * 64 + mi * 16 + kgrp * 4;
        int col = n0 + wn * 64 + ni * 16 + row16;
        int bb = mb >> 11, s = mb & 2047;
        unsigned int p0 = (unsigned int)f2bu(acc[mi][ni][0]) | ((unsigned int)f2bu(acc[mi][ni][1]) << 16);
        unsigned int p1 = (unsigned int)f2bu(acc[mi][ni][2]) | ((unsigned int)f2bu(acc[mi][ni][3]) << 16);
        uint2 pk; pk.x = p0; pk.y = p1;
        *(uint2*)&Vt[(((size_t)(bb * 1024 + col)) << 11) + s] = pk;
      }
  }
}

// output projection: out = attn(f32) * Wo(bf16)^T, f32 out. 1D grid 256, XCD-aware.
__global__ __launch_bounds__(256) void gemm_wo(const float* __restrict__ A,
                                               const unsigned short* __restrict__ Bw,
                                               float* __restrict__ C) {
  __shared__ unsigned short As[128][64];
  __shared__ unsigned short Bs[128][64];
  const int xcd = blockIdx.x & 7, u = blockIdx.x >> 3;   // u 0..31
  const int g = xcd * 4 + (u >> 3);                      // m-strip 0..31
  const int m0 = g * 128, n0 = (u & 7) * 128;

  f32x4 acc[4][4] = {};
  gemm_core(A, Bw, m0, n0, acc, As, Bs);

  const int lane = threadIdx.x & 63, wave = threadIdx.x >> 6;
  const int wm = wave >> 1, wn = wave & 1;
  const int row16 = lane & 15, kgrp = lane >> 4;
#pragma unroll
  for (int mi = 0; mi < 4; mi++)
#pragma unroll
    for (int ni = 0; ni < 4; ni++)
#pragma unroll
      for (int r = 0; r < 4; r++) {
        int row = m0 + wm * 64 + mi * 16 + kgrp * 4 + r;
        int col = n0 + wn * 64 + ni * 16 + row16;
        C[(size_t)row * 1024 + col] = acc[mi][ni][r];
      }
}

// ---------------------------------------------------------------- first unmasked key per batch
__global__ __launch_bounds__(256) void fu_kernel(const int* __restrict__ mask, int* __restrict__ fu) {
  const int S = 2048;
  int b = blockIdx.x;
  __shared__ int red[256];
  int best = S;
  for (int k = threadIdx.x; k < S; k += 256)
    if (mask[b * S + k] != 0 && k < best) best = k;
  red[threadIdx.x] = best;
  __syncthreads();
  for (int s = 128; s > 0; s >>= 1) {
    if (threadIdx.x < s) red[threadIdx.x] = min(red[threadIdx.x], red[threadIdx.x + s]);
    __syncthreads();
  }
  if (threadIdx.x == 0) fu[b] = red[0];
}

// ---------------------------------------------------------------- V column sums from Vt (deterministic)
__global__ __launch_bounds__(256) void reduce_vt(const unsigned short* __restrict__ Vt,
                                                 float* __restrict__ vsum) {
  __shared__ float red[256];
  const unsigned short* p = Vt + ((size_t)blockIdx.x << 11) + threadIdx.x * 8;
  uint4 u = *(const uint4*)p;
  float s = b2f((unsigned short)(u.x & 0xffff));
  s += b2f((unsigned short)(u.x >> 16));
  s += b2f((unsigned short)(u.y & 0xffff));
  s += b2f((unsigned short)(u.y >> 16));
  s += b2f((unsigned short)(u.z & 0xffff));
  s += b2f((unsigned short)(u.z >> 16));
  s += b2f((unsigned short)(u.w & 0xffff));
  s += b2f((unsigned short)(u.w >> 16));
  red[threadIdx.x] = s;
  __syncthreads();
  for (int st = 128; st > 0; st >>= 1) {
    if (threadIdx.x < st) red[threadIdx.x] += red[threadIdx.x + st];
    __syncthreads();
  }
  if (threadIdx.x == 0) vsum[blockIdx.x] = red[0];
}

// ---------------------------------------------------------------- flash attention v4
// Swapped QK^T (S^T = mfma(K,Q)) so q is lane-local: in-lane softmax + 2 shfl.
// PV as O^T = mfma(V^T, P^T). 512 blocks, each owns q-tile pair (qt, 31-qt) = 33 k-tiles.
__global__ __launch_bounds__(256) void flash_attn4(const unsigned short* __restrict__ Q,
                                                   const unsigned short* __restrict__ Kp,
                                                   const unsigned short* __restrict__ Vt,
                                                   const int* __restrict__ mask,
                                                   const int* __restrict__ fu,
                                                   const float* __restrict__ vsum,
                                                   float* __restrict__ O) {
  const int S = 2048, DM = 1024;
  const int xcd = blockIdx.x & 7, idx = blockIdx.x >> 3;   // 64 blocks per XCD
  const int bh = xcd * 4 + (idx >> 4);                     // 4 (b,h) per XCD -> ~3MB L2 set
  const int pairq = idx & 15;
  const int b = bh >> 4, h = bh & 15;
  const int tid = threadIdx.x, lane = tid & 63, wave = tid >> 6;
  const int row16 = lane & 15, kgrp = lane >> 4;

  __shared__ unsigned short Ks[2][64][64];   // 16 KB, XOR-swizzled 8B slots
  __shared__ unsigned short Vs[2][64][64];   // 16 KB (V^T tile: rows=d, cols=k), swizzled
  __shared__ unsigned short Ps[4][16][72];   // per-wave P [q][k], padded rows

  const size_t base = ((size_t)b * S) * DM + h * 64;
  const size_t vtb = ((size_t)(b * 1024 + h * 64)) * S;
  const int* maskb = mask + b * S;

  const int srow = lane >> 3;
  const int sslot = (lane & 7) ^ srow;

  const int fub = fu[b];
  const float* vs = vsum + b * DM + h * 64;
  const int sw = row16 & 7;

#pragma unroll
  for (int pass = 0; pass < 2; ++pass) {
    const int qt = pass ? (31 - pairq) : pairq;
    const int q0 = qt * 64 + wave * 16;
    const int qg = q0 + row16;                 // this lane's q row (lane-local!)
    const int nt = qt + 1;

    s16x8 qf0 = *(const s16x8*)&Q[base + (size_t)qg * DM + kgrp * 8];
    s16x8 qf1 = *(const s16x8*)&Q[base + (size_t)qg * DM + 32 + kgrp * 8];

    f32x4 oacc[4] = {};
    float m_run = -1e30f, l_run = 0.f;

    auto stage = [&](int t, int bf) {
      const int kb = t * 64;
#pragma unroll
      for (int c2 = 0; c2 < 2; c2++) {
        const int r = wave * 16 + c2 * 8 + srow;
        GLD16(Kp + base + (size_t)(kb + r) * DM + sslot * 8,
              (char*)&Ks[bf][0][0] + (wave * 2 + c2) * 1024);
        GLD16(Vt + vtb + (size_t)r * S + kb + sslot * 8,
              (char*)&Vs[bf][0][0] + (wave * 2 + c2) * 1024);
      }
    };

    stage(0, 0);
    asm volatile("s_waitcnt vmcnt(0)" ::: "memory");
    __syncthreads();

    int cur = 0;
    for (int t = 0; t < nt; ++t) {
      if (t + 1 < nt) stage(t + 1, cur ^ 1);
      const int kb = t * 64;

      // S^T = K * Q^T : lane holds scores for q=qg, k = kb + nf*16 + kgrp*4 + r
      f32x4 sc[4];
#pragma unroll
      for (int nf = 0; nf < 4; nf++) {
        const int rr = nf * 16 + row16;
        s16x8 k0 = *(const s16x8*)&Ks[cur][rr][(kgrp ^ sw) * 8];
        s16x8 k1 = *(const s16x8*)&Ks[cur][rr][((4 + kgrp) ^ sw) * 8];
        f32x4 a = {};
        a = MFMA16(k0, qf0, a);
        a = MFMA16(k1, qf1, a);
        sc[nf] = a;
      }

      // scale + pad mask + causal (exact NEG = -10000 semantics)
#pragma unroll
      for (int nf = 0; nf < 4; nf++) {
        const int kbase = kb + nf * 16 + kgrp * 4;
        int4 mv = *(const int4*)&maskb[kbase];
#pragma unroll
        for (int r = 0; r < 4; r++) {
          int m_ok = (r == 0) ? mv.x : (r == 1) ? mv.y : (r == 2) ? mv.z : mv.w;
          float s = sc[nf][r] * 0.125f;
          sc[nf][r] = (kbase + r > qg || m_ok == 0) ? -10000.0f : s;
        }
      }

      // softmax: in-lane over 16, then 2 shfl over the 4 lanes sharing this q
      float t01 = fmaxf(fmaxf(sc[0][0], sc[0][1]), fmaxf(sc[0][2], sc[0][3]));
      float t23 = fmaxf(fmaxf(sc[1][0], sc[1][1]), fmaxf(sc[1][2], sc[1][3]));
      float t45 = fmaxf(fmaxf(sc[2][0], sc[2][1]), fmaxf(sc[2][2], sc[2][3]));
      float t67 = fmaxf(fmaxf(sc[3][0], sc[3][1]), fmaxf(sc[3][2], sc[3][3]));
      float tmax = fmaxf(fmaxf(t01, t23), fmaxf(t45, t67));
      tmax = fmaxf(tmax, __shfl_xor(tmax, 16));
      tmax = fmaxf(tmax, __shfl_xor(tmax, 32));

      float mnew = fmaxf(m_run, tmax);
      float alpha = __expf(m_run - mnew);
      m_run = mnew;

      float rsum = 0.f;
#pragma unroll
      for (int nf = 0; nf < 4; nf++)
#pragma unroll
        for (int r = 0; r < 4; r++) {
          float p = __expf(sc[nf][r] - mnew);
          sc[nf][r] = p;
          rsum += p;
        }
      rsum += __shfl_xor(rsum, 16);
      rsum += __shfl_xor(rsum, 32);
      l_run = l_run * alpha + rsum;
#pragma unroll
      for (int nf2 = 0; nf2 < 4; nf2++)
#pragma unroll
        for (int r = 0; r < 4; r++) oacc[nf2][r] *= alpha;

      // P pack: 4 consecutive k per nf -> one 8B write each
#pragma unroll
      for (int nf = 0; nf < 4; nf++) {
        uint2 pk;
        pk.x = (unsigned int)f2bu(sc[nf][0]) | ((unsigned int)f2bu(sc[nf][1]) << 16);
        pk.y = (unsigned int)f2bu(sc[nf][2]) | ((unsigned int)f2bu(sc[nf][3]) << 16);
        *(uint2*)&Ps[wave][row16][nf * 16 + kgrp * 4] = pk;
      }
      // B-frag of P^T: lane holds P[q=row16][k=kk*32+kgrp*8+j] (wave-local, no barrier)
      s16x8 pf0 = *(const s16x8*)&Ps[wave][row16][kgrp * 8];
      s16x8 pf1 = *(const s16x8*)&Ps[wave][row16][32 + kgrp * 8];

      // O^T += V^T * P^T
#pragma unroll
      for (int nf2 = 0; nf2 < 4; nf2++) {
        const int rr = nf2 * 16 + row16;
        s16x8 v0 = *(const s16x8*)&Vs[cur][rr][(kgrp ^ sw) * 8];
        s16x8 v1 = *(const s16x8*)&Vs[cur][rr][((4 + kgrp) ^ sw) * 8];
        oacc[nf2] = MFMA16(v0, pf0, oacc[nf2]);
        oacc[nf2] = MFMA16(v1, pf1, oacc[nf2]);
      }

      asm volatile("s_waitcnt vmcnt(0)" ::: "memory");
      __syncthreads();
      cur ^= 1;
    }

    // epilogue: lane owns q=qg, d = nf2*16 + kgrp*4 + r -> float4 stores
    const float rl = 1.0f / l_run;
#pragma unroll
    for (int nf2 = 0; nf2 < 4; nf2++) {
      const int d0 = nf2 * 16 + kgrp * 4;
      float4 val;
      val.x = oacc[nf2][0] * rl;
      val.y = oacc[nf2][1] * rl;
      val.z = oacc[nf2][2] * rl;
      val.w = oacc[nf2][3] * rl;
      if (qg < fub) {
        float4 vv = *(const float4*)&vs[d0];
        val.x = vv.x * (1.0f / 2048.0f);
        val.y = vv.y * (1.0f / 2048.0f);
        val.z = vv.z * (1.0f / 2048.0f);
        val.w = vv.w * (1.0f / 2048.0f);
      }
      *(float4*)&O[base + (size_t)qg * DM + d0] = val;
    }
  }
}

// ---------------------------------------------------------------- launch
extern "C" void kernel_launch(void* const* d_in, const int* in_sizes, int n_in,
                              void* d_out, int out_size, void* d_ws, size_t ws_size,
                              hipStream_t stream) {
  const float* q    = (const float*)d_in[0];
  const float* k    = (const float*)d_in[1];
  const float* v    = (const float*)d_in[2];
  const int*   mask = (const int*)d_in[3];
  const float* Wq   = (const float*)d_in[4];
  const float* Wk   = (const float*)d_in[5];
  const float* Wv   = (const float*)d_in[6];
  const float* Wo   = (const float*)d_in[7];
  float* out = (float*)d_out;
  char* ws = (char*)d_ws;

  unsigned short* Wqb = (unsigned short*)(ws + (size_t)0);
  unsigned short* Wkb = (unsigned short*)(ws + ((size_t)2 << 20));
  unsigned short* Wvb = (unsigned short*)(ws + ((size_t)4 << 20));
  unsigned short* Wob = (unsigned short*)(ws + ((size_t)6 << 20));
  unsigned short* Qb  = (unsigned short*)(ws + ((size_t)8 << 20));
  unsigned short* Kb  = (unsigned short*)(ws + ((size_t)16 << 20));
  unsigned short* Vt  = (unsigned short*)(ws + ((size_t)24 << 20));
  float* attn = (float*)(ws + ((size_t)32 << 20));
  float* vsum = (float*)(ws + ((size_t)48 << 20));
  int*   fub  = (int*)(ws + ((size_t)48 << 20) + (64 << 10));

  cast_w4<<<dim3(1024, 4), 256, 0, stream>>>(Wq, Wk, Wv, Wo, Wqb, Wkb, Wvb, Wob);

  qkv_gemm<<<768, 256, 0, stream>>>(q, k, v, Wqb, Wkb, Wvb, Qb, Kb, Vt);

  fu_kernel<<<2, 256, 0, stream>>>(mask, fub);
  reduce_vt<<<2048, 256, 0, stream>>>(Vt, vsum);

  flash_attn4<<<512, 256, 0, stream>>>(Qb, Kb, Vt, mask, fub, vsum, attn);

  gemm_wo<<<256, 256, 0, stream>>>(attn, Wob, out);
}

// Round 6
// 151.248 us; speedup vs baseline: 2.0893x; 1.0537x over previous
//
#include <hip/hip_runtime.h>
#include <hip/hip_bf16.h>

typedef __attribute__((ext_vector_type(8))) short s16x8;
typedef __attribute__((ext_vector_type(4))) float f32x4;

#define MFMA16(a,b,c) __builtin_amdgcn_mfma_f32_16x16x32_bf16((a),(b),(c),0,0,0)

#define GLD16(gp, lp) __builtin_amdgcn_global_load_lds( \
  (const __attribute__((address_space(1))) unsigned int*)(gp), \
  (__attribute__((address_space(3))) unsigned int*)(lp), 16, 0, 0)

static __device__ __forceinline__ unsigned short f2bu(float f) {
  __hip_bfloat16 h = __float2bfloat16(f);
  unsigned short u; __builtin_memcpy(&u, &h, 2); return u;
}
static __device__ __forceinline__ float b2f(unsigned short u) {
  unsigned int x = ((unsigned int)u) << 16; float f; __builtin_memcpy(&f, &x, 4); return f;
}

// ---------------------------------------------------------------- cast activations + weights, one launch
__global__ __launch_bounds__(256) void cast_all(const float* __restrict__ q, const float* __restrict__ k,
                                                const float* __restrict__ v,
                                                const float* __restrict__ Wq, const float* __restrict__ Wk,
                                                const float* __restrict__ Wv, const float* __restrict__ Wo,
                                                unsigned short* __restrict__ qc, unsigned short* __restrict__ kc,
                                                unsigned short* __restrict__ vc,
                                                unsigned short* __restrict__ wq, unsigned short* __restrict__ wk,
                                                unsigned short* __restrict__ wv, unsigned short* __restrict__ wo) {
  const int y = blockIdx.y;
  const float* in; unsigned short* out; int n4;
  switch (y) {
    case 0: in = q;  out = qc; n4 = 1048576; break;
    case 1: in = k;  out = kc; n4 = 1048576; break;
    case 2: in = v;  out = vc; n4 = 1048576; break;
    case 3: in = Wq; out = wq; n4 = 262144; break;
    case 4: in = Wk; out = wk; n4 = 262144; break;
    case 5: in = Wv; out = wv; n4 = 262144; break;
    default: in = Wo; out = wo; n4 = 262144; break;
  }
  int i = blockIdx.x * 256 + threadIdx.x;
  if (i < n4) {
    float4 val = *(const float4*)(in + (size_t)i * 4);
    unsigned int p0 = (unsigned int)f2bu(val.x) | ((unsigned int)f2bu(val.y) << 16);
    unsigned int p1 = (unsigned int)f2bu(val.z) | ((unsigned int)f2bu(val.w) << 16);
    uint2 pk; pk.x = p0; pk.y = p1;
    *(uint2*)(out + (size_t)i * 4) = pk;
  }
}

// ---------------------------------------------------------------- shared GEMM core: C = A(bf16) * Bw(bf16)^T
// Both tiles staged via global_load_lds with pre-swizzled SOURCE; XOR-swizzled ds_read_b128.
static __device__ __forceinline__ void gemm_core(const unsigned short* __restrict__ Aw,
                                                 const unsigned short* __restrict__ Bw,
                                                 int m0, int n0,
                                                 f32x4 (&acc)[4][4],
                                                 unsigned short (*As)[64], unsigned short (*Bs)[64]) {
  const int K = 1024;
  const int tid = threadIdx.x;
  const int lane = tid & 63, wave = tid >> 6;
  const int wm = wave >> 1, wn = wave & 1;
  const int row16 = lane & 15, kgrp = lane >> 4;
  const int srow = lane >> 3, sslot = (lane & 7) ^ srow;
  const int sw = row16 & 7;

  for (int k0 = 0; k0 < K; k0 += 64) {
#pragma unroll
    for (int i = 0; i < 4; i++) {
      int rr = (wave * 4 + i) * 8 + srow;
      GLD16(Aw + (size_t)(m0 + rr) * K + k0 + sslot * 8, (char*)As + (wave * 4 + i) * 1024);
      GLD16(Bw + (size_t)(n0 + rr) * K + k0 + sslot * 8, (char*)Bs + (wave * 4 + i) * 1024);
    }
    __syncthreads();

#pragma unroll
    for (int kk = 0; kk < 2; kk++) {
      s16x8 af[4], bfr[4];
#pragma unroll
      for (int mi = 0; mi < 4; mi++) {
        int rr = wm * 64 + mi * 16 + row16;
        af[mi] = *(const s16x8*)((char*)&As[rr][0] + ((kk * 4 + kgrp) ^ sw) * 16);
      }
#pragma unroll
      for (int ni = 0; ni < 4; ni++) {
        int rr = wn * 64 + ni * 16 + row16;
        bfr[ni] = *(const s16x8*)((char*)&Bs[rr][0] + ((kk * 4 + kgrp) ^ sw) * 16);
      }
#pragma unroll
      for (int mi = 0; mi < 4; mi++)
#pragma unroll
        for (int ni = 0; ni < 4; ni++)
          acc[mi][ni] = MFMA16(af[mi], bfr[ni], acc[mi][ni]);
    }
    __syncthreads();
  }
}

// fused Q/K/V projection, 1D grid 768, XCD-aware. z=2 writes Vt transposed.
__global__ __launch_bounds__(256) void qkv_gemm(const unsigned short* __restrict__ qc,
                                                const unsigned short* __restrict__ kc,
                                                const unsigned short* __restrict__ vc,
                                                const unsigned short* __restrict__ Wqb,
                                                const unsigned short* __restrict__ Wkb,
                                                const unsigned short* __restrict__ Wvb,
                                                unsigned short* __restrict__ Qb,
                                                unsigned short* __restrict__ Kb,
                                                unsigned short* __restrict__ Vt) {
  __shared__ unsigned short As[128][64];
  __shared__ unsigned short Bs[128][64];
  const int xcd = blockIdx.x & 7, u = blockIdx.x >> 3;   // u 0..95
  const int g = xcd * 12 + (u >> 3);                     // unit 0..95
  const int z = g >> 5, mstrip = g & 31;
  const int m0 = mstrip * 128, n0 = (u & 7) * 128;

  const unsigned short* A = (z == 0) ? qc : (z == 1) ? kc : vc;
  const unsigned short* Bw = (z == 0) ? Wqb : (z == 1) ? Wkb : Wvb;

  f32x4 acc[4][4] = {};
  gemm_core(A, Bw, m0, n0, acc, As, Bs);

  const int lane = threadIdx.x & 63, wave = threadIdx.x >> 6;
  const int wm = wave >> 1, wn = wave & 1;
  const int row16 = lane & 15, kgrp = lane >> 4;

  if (z < 2) {
    unsigned short* C = z ? Kb : Qb;
#pragma unroll
    for (int mi = 0; mi < 4; mi++)
#pragma unroll
      for (int ni = 0; ni < 4; ni++)
#pragma unroll
        for (int r = 0; r < 4; r++) {
          int row = m0 + wm * 64 + mi * 16 + kgrp * 4 + r;
          int col = n0 + wn * 64 + ni * 16 + row16;
          C[(size_t)row * 1024 + col] = f2bu(acc[mi][ni][r]);
        }
  } else {
#pragma unroll
    for (int mi = 0; mi < 4; mi++)
#pragma unroll
      for (int ni = 0; ni < 4; ni++) {
        int mb = m0 + wm * 64 + mi * 16 + kgrp * 4;
        int col = n0 + wn * 64 + ni * 16 + row16;
        int bb = mb >> 11, s = mb & 2047;
        unsigned int p0 = (unsigned int)f2bu(acc[mi][ni][0]) | ((unsigned int)f2bu(acc[mi][ni][1]) << 16);
        unsigned int p1 = (unsigned int)f2bu(acc[mi][ni][2]) | ((unsigned int)f2bu(acc[mi][ni][3]) << 16);
        uint2 pk; pk.x = p0; pk.y = p1;
        *(uint2*)&Vt[(((size_t)(bb * 1024 + col)) << 11) + s] = pk;
      }
  }
}

// output projection: out = attn(bf16) * Wo(bf16)^T, f32 out. 1D grid 256, XCD-aware.
__global__ __launch_bounds__(256) void gemm_wo(const unsigned short* __restrict__ A,
                                               const unsigned short* __restrict__ Bw,
                                               float* __restrict__ C) {
  __shared__ unsigned short As[128][64];
  __shared__ unsigned short Bs[128][64];
  const int xcd = blockIdx.x & 7, u = blockIdx.x >> 3;   // u 0..31
  const int g = xcd * 4 + (u >> 3);                      // m-strip 0..31
  const int m0 = g * 128, n0 = (u & 7) * 128;

  f32x4 acc[4][4] = {};
  gemm_core(A, Bw, m0, n0, acc, As, Bs);

  const int lane = threadIdx.x & 63, wave = threadIdx.x >> 6;
  const int wm = wave >> 1, wn = wave & 1;
  const int row16 = lane & 15, kgrp = lane >> 4;
#pragma unroll
  for (int mi = 0; mi < 4; mi++)
#pragma unroll
    for (int ni = 0; ni < 4; ni++)
#pragma unroll
      for (int r = 0; r < 4; r++) {
        int row = m0 + wm * 64 + mi * 16 + kgrp * 4 + r;
        int col = n0 + wn * 64 + ni * 16 + row16;
        C[(size_t)row * 1024 + col] = acc[mi][ni][r];
      }
}

// ---------------------------------------------------------------- first unmasked key per batch
__global__ __launch_bounds__(256) void fu_kernel(const int* __restrict__ mask, int* __restrict__ fu) {
  const int S = 2048;
  int b = blockIdx.x;
  __shared__ int red[256];
  int best = S;
  for (int k = threadIdx.x; k < S; k += 256)
    if (mask[b * S + k] != 0 && k < best) best = k;
  red[threadIdx.x] = best;
  __syncthreads();
  for (int s = 128; s > 0; s >>= 1) {
    if (threadIdx.x < s) red[threadIdx.x] = min(red[threadIdx.x], red[threadIdx.x + s]);
    __syncthreads();
  }
  if (threadIdx.x == 0) fu[b] = red[0];
}

// ---------------------------------------------------------------- V column sums from Vt (deterministic)
__global__ __launch_bounds__(256) void reduce_vt(const unsigned short* __restrict__ Vt,
                                                 float* __restrict__ vsum) {
  __shared__ float red[256];
  const unsigned short* p = Vt + ((size_t)blockIdx.x << 11) + threadIdx.x * 8;
  uint4 u = *(const uint4*)p;
  float s = b2f((unsigned short)(u.x & 0xffff));
  s += b2f((unsigned short)(u.x >> 16));
  s += b2f((unsigned short)(u.y & 0xffff));
  s += b2f((unsigned short)(u.y >> 16));
  s += b2f((unsigned short)(u.z & 0xffff));
  s += b2f((unsigned short)(u.z >> 16));
  s += b2f((unsigned short)(u.w & 0xffff));
  s += b2f((unsigned short)(u.w >> 16));
  red[threadIdx.x] = s;
  __syncthreads();
  for (int st = 128; st > 0; st >>= 1) {
    if (threadIdx.x < st) red[threadIdx.x] += red[threadIdx.x + st];
    __syncthreads();
  }
  if (threadIdx.x == 0) vsum[blockIdx.x] = red[0];
}

// ---------------------------------------------------------------- flash attention v4 (bf16 output)
__global__ __launch_bounds__(256) void flash_attn4(const unsigned short* __restrict__ Q,
                                                   const unsigned short* __restrict__ Kp,
                                                   const unsigned short* __restrict__ Vt,
                                                   const int* __restrict__ mask,
                                                   const int* __restrict__ fu,
                                                   const float* __restrict__ vsum,
                                                   unsigned short* __restrict__ O) {
  const int S = 2048, DM = 1024;
  const int xcd = blockIdx.x & 7, idx = blockIdx.x >> 3;   // 64 blocks per XCD
  const int bh = xcd * 4 + (idx >> 4);                     // 4 (b,h) per XCD -> ~3MB L2 set
  const int pairq = idx & 15;
  const int b = bh >> 4, h = bh & 15;
  const int tid = threadIdx.x, lane = tid & 63, wave = tid >> 6;
  const int row16 = lane & 15, kgrp = lane >> 4;

  __shared__ unsigned short Ks[2][64][64];   // 16 KB, XOR-swizzled 8B slots
  __shared__ unsigned short Vs[2][64][64];   // 16 KB (V^T tile: rows=d, cols=k), swizzled
  __shared__ unsigned short Ps[4][16][72];   // per-wave P [q][k], padded rows

  const size_t base = ((size_t)b * S) * DM + h * 64;
  const size_t vtb = ((size_t)(b * 1024 + h * 64)) * S;
  const int* maskb = mask + b * S;

  const int srow = lane >> 3;
  const int sslot = (lane & 7) ^ srow;

  const int fub = fu[b];
  const float* vs = vsum + b * DM + h * 64;
  const int sw = row16 & 7;

#pragma unroll
  for (int pass = 0; pass < 2; ++pass) {
    const int qt = pass ? (31 - pairq) : pairq;
    const int q0 = qt * 64 + wave * 16;
    const int qg = q0 + row16;                 // this lane's q row (lane-local!)
    const int nt = qt + 1;

    s16x8 qf0 = *(const s16x8*)&Q[base + (size_t)qg * DM + kgrp * 8];
    s16x8 qf1 = *(const s16x8*)&Q[base + (size_t)qg * DM + 32 + kgrp * 8];

    f32x4 oacc[4] = {};
    float m_run = -1e30f, l_run = 0.f;

    auto stage = [&](int t, int bf) {
      const int kb = t * 64;
#pragma unroll
      for (int c2 = 0; c2 < 2; c2++) {
        const int r = wave * 16 + c2 * 8 + srow;
        GLD16(Kp + base + (size_t)(kb + r) * DM + sslot * 8,
              (char*)&Ks[bf][0][0] + (wave * 2 + c2) * 1024);
        GLD16(Vt + vtb + (size_t)r * S + kb + sslot * 8,
              (char*)&Vs[bf][0][0] + (wave * 2 + c2) * 1024);
      }
    };

    stage(0, 0);
    asm volatile("s_waitcnt vmcnt(0)" ::: "memory");
    __syncthreads();

    int cur = 0;
    for (int t = 0; t < nt; ++t) {
      if (t + 1 < nt) stage(t + 1, cur ^ 1);
      const int kb = t * 64;

      // S^T = K * Q^T : lane holds scores for q=qg, k = kb + nf*16 + kgrp*4 + r
      f32x4 sc[4];
#pragma unroll
      for (int nf = 0; nf < 4; nf++) {
        const int rr = nf * 16 + row16;
        s16x8 k0 = *(const s16x8*)&Ks[cur][rr][(kgrp ^ sw) * 8];
        s16x8 k1 = *(const s16x8*)&Ks[cur][rr][((4 + kgrp) ^ sw) * 8];
        f32x4 a = {};
        a = MFMA16(k0, qf0, a);
        a = MFMA16(k1, qf1, a);
        sc[nf] = a;
      }

      // scale + pad mask + causal (exact NEG = -10000 semantics)
#pragma unroll
      for (int nf = 0; nf < 4; nf++) {
        const int kbase = kb + nf * 16 + kgrp * 4;
        int4 mv = *(const int4*)&maskb[kbase];
#pragma unroll
        for (int r = 0; r < 4; r++) {
          int m_ok = (r == 0) ? mv.x : (r == 1) ? mv.y : (r == 2) ? mv.z : mv.w;
          float s = sc[nf][r] * 0.125f;
          sc[nf][r] = (kbase + r > qg || m_ok == 0) ? -10000.0f : s;
        }
      }

      // softmax: in-lane over 16, then 2 shfl over the 4 lanes sharing this q
      float t01 = fmaxf(fmaxf(sc[0][0], sc[0][1]), fmaxf(sc[0][2], sc[0][3]));
      float t23 = fmaxf(fmaxf(sc[1][0], sc[1][1]), fmaxf(sc[1][2], sc[1][3]));
      float t45 = fmaxf(fmaxf(sc[2][0], sc[2][1]), fmaxf(sc[2][2], sc[2][3]));
      float t67 = fmaxf(fmaxf(sc[3][0], sc[3][1]), fmaxf(sc[3][2], sc[3][3]));
      float tmax = fmaxf(fmaxf(t01, t23), fmaxf(t45, t67));
      tmax = fmaxf(tmax, __shfl_xor(tmax, 16));
      tmax = fmaxf(tmax, __shfl_xor(tmax, 32));

      float mnew = fmaxf(m_run, tmax);
      float alpha = __expf(m_run - mnew);
      m_run = mnew;

      float rsum = 0.f;
#pragma unroll
      for (int nf = 0; nf < 4; nf++)
#pragma unroll
        for (int r = 0; r < 4; r++) {
          float p = __expf(sc[nf][r] - mnew);
          sc[nf][r] = p;
          rsum += p;
        }
      rsum += __shfl_xor(rsum, 16);
      rsum += __shfl_xor(rsum, 32);
      l_run = l_run * alpha + rsum;
#pragma unroll
      for (int nf2 = 0; nf2 < 4; nf2++)
#pragma unroll
        for (int r = 0; r < 4; r++) oacc[nf2][r] *= alpha;

      // P pack: 4 consecutive k per nf -> one 8B write each
#pragma unroll
      for (int nf = 0; nf < 4; nf++) {
        uint2 pk;
        pk.x = (unsigned int)f2bu(sc[nf][0]) | ((unsigned int)f2bu(sc[nf][1]) << 16);
        pk.y = (unsigned int)f2bu(sc[nf][2]) | ((unsigned int)f2bu(sc[nf][3]) << 16);
        *(uint2*)&Ps[wave][row16][nf * 16 + kgrp * 4] = pk;
      }
      // B-frag of P^T: lane holds P[q=row16][k=kk*32+kgrp*8+j] (wave-local, no barrier)
      s16x8 pf0 = *(const s16x8*)&Ps[wave][row16][kgrp * 8];
      s16x8 pf1 = *(const s16x8*)&Ps[wave][row16][32 + kgrp * 8];

      // O^T += V^T * P^T
#pragma unroll
      for (int nf2 = 0; nf2 < 4; nf2++) {
        const int rr = nf2 * 16 + row16;
        s16x8 v0 = *(const s16x8*)&Vs[cur][rr][(kgrp ^ sw) * 8];
        s16x8 v1 = *(const s16x8*)&Vs[cur][rr][((4 + kgrp) ^ sw) * 8];
        oacc[nf2] = MFMA16(v0, pf0, oacc[nf2]);
        oacc[nf2] = MFMA16(v1, pf1, oacc[nf2]);
      }

      asm volatile("s_waitcnt vmcnt(0)" ::: "memory");
      __syncthreads();
      cur ^= 1;
    }

    // epilogue: lane owns q=qg, d = nf2*16 + kgrp*4 + r -> packed bf16 stores
    const float rl = 1.0f / l_run;
#pragma unroll
    for (int nf2 = 0; nf2 < 4; nf2++) {
      const int d0 = nf2 * 16 + kgrp * 4;
      float v0 = oacc[nf2][0] * rl, v1 = oacc[nf2][1] * rl;
      float v2 = oacc[nf2][2] * rl, v3 = oacc[nf2][3] * rl;
      if (qg < fub) {
        float4 vv = *(const float4*)&vs[d0];
        v0 = vv.x * (1.0f / 2048.0f);
        v1 = vv.y * (1.0f / 2048.0f);
        v2 = vv.z * (1.0f / 2048.0f);
        v3 = vv.w * (1.0f / 2048.0f);
      }
      uint2 pk;
      pk.x = (unsigned int)f2bu(v0) | ((unsigned int)f2bu(v1) << 16);
      pk.y = (unsigned int)f2bu(v2) | ((unsigned int)f2bu(v3) << 16);
      *(uint2*)&O[base + (size_t)qg * DM + d0] = pk;
    }
  }
}

// ---------------------------------------------------------------- launch
extern "C" void kernel_launch(void* const* d_in, const int* in_sizes, int n_in,
                              void* d_out, int out_size, void* d_ws, size_t ws_size,
                              hipStream_t stream) {
  const float* q    = (const float*)d_in[0];
  const float* k    = (const float*)d_in[1];
  const float* v    = (const float*)d_in[2];
  const int*   mask = (const int*)d_in[3];
  const float* Wq   = (const float*)d_in[4];
  const float* Wk   = (const float*)d_in[5];
  const float* Wv   = (const float*)d_in[6];
  const float* Wo   = (const float*)d_in[7];
  float* out = (float*)d_out;
  char* ws = (char*)d_ws;

  // ws layout (<= ~40.1 MB):
  unsigned short* Wqb  = (unsigned short*)(ws + (size_t)0);
  unsigned short* Wkb  = (unsigned short*)(ws + ((size_t)2 << 20));
  unsigned short* Wvb  = (unsigned short*)(ws + ((size_t)4 << 20));
  unsigned short* Wob  = (unsigned short*)(ws + ((size_t)6 << 20));
  unsigned short* vc   = (unsigned short*)(ws + ((size_t)8 << 20));   // vcast, dead after qkv_gemm
  unsigned short* attn = (unsigned short*)(ws + ((size_t)8 << 20));   // aliases vc (flash runs later)
  unsigned short* Qb   = (unsigned short*)(ws + ((size_t)16 << 20));
  unsigned short* Kb   = (unsigned short*)(ws + ((size_t)24 << 20));
  unsigned short* Vt   = (unsigned short*)(ws + ((size_t)32 << 20));
  float* vsum          = (float*)(ws + ((size_t)40 << 20));
  int*   fub           = (int*)(ws + ((size_t)40 << 20) + (64 << 10));
  // d_out (16 MB f32) used as scratch for q/k casts; fully overwritten by gemm_wo at the end.
  unsigned short* qc   = (unsigned short*)d_out;
  unsigned short* kc   = (unsigned short*)d_out + 4194304;

  cast_all<<<dim3(4096, 7), 256, 0, stream>>>(q, k, v, Wq, Wk, Wv, Wo,
                                              qc, kc, vc, Wqb, Wkb, Wvb, Wob);

  qkv_gemm<<<768, 256, 0, stream>>>(qc, kc, vc, Wqb, Wkb, Wvb, Qb, Kb, Vt);

  fu_kernel<<<2, 256, 0, stream>>>(mask, fub);
  reduce_vt<<<2048, 256, 0, stream>>>(Vt, vsum);

  flash_attn4<<<512, 256, 0, stream>>>(Qb, Kb, Vt, mask, fub, vsum, attn);

  gemm_wo<<<256, 256, 0, stream>>>(attn, Wob, out);
}

// Round 7
// 144.842 us; speedup vs baseline: 2.1817x; 1.0442x over previous
//
#include <hip/hip_runtime.h>
#include <hip/hip_bf16.h>
#include <math.h>

typedef __attribute__((ext_vector_type(8))) short s16x8;
typedef __attribute__((ext_vector_type(4))) float f32x4;

#define MFMA16(a,b,c) __builtin_amdgcn_mfma_f32_16x16x32_bf16((a),(b),(c),0,0,0)

#define GLD16(gp, lp) __builtin_amdgcn_global_load_lds( \
  (const __attribute__((address_space(1))) unsigned int*)(gp), \
  (__attribute__((address_space(3))) unsigned int*)(lp), 16, 0, 0)

static __device__ __forceinline__ unsigned short f2bu(float f) {
  __hip_bfloat16 h = __float2bfloat16(f);
  unsigned short u; __builtin_memcpy(&u, &h, 2); return u;
}
static __device__ __forceinline__ float b2f(unsigned short u) {
  unsigned int x = ((unsigned int)u) << 16; float f; __builtin_memcpy(&f, &x, 4); return f;
}

// ---------------------------------------------------------------- cast activations + weights, one launch
__global__ __launch_bounds__(256) void cast_all(const float* __restrict__ q, const float* __restrict__ k,
                                                const float* __restrict__ v,
                                                const float* __restrict__ Wq, const float* __restrict__ Wk,
                                                const float* __restrict__ Wv, const float* __restrict__ Wo,
                                                unsigned short* __restrict__ qc, unsigned short* __restrict__ kc,
                                                unsigned short* __restrict__ vc,
                                                unsigned short* __restrict__ wq, unsigned short* __restrict__ wk,
                                                unsigned short* __restrict__ wv, unsigned short* __restrict__ wo) {
  const int y = blockIdx.y;
  const float* in; unsigned short* out; int n4;
  switch (y) {
    case 0: in = q;  out = qc; n4 = 1048576; break;
    case 1: in = k;  out = kc; n4 = 1048576; break;
    case 2: in = v;  out = vc; n4 = 1048576; break;
    case 3: in = Wq; out = wq; n4 = 262144; break;
    case 4: in = Wk; out = wk; n4 = 262144; break;
    case 5: in = Wv; out = wv; n4 = 262144; break;
    default: in = Wo; out = wo; n4 = 262144; break;
  }
  int i = blockIdx.x * 256 + threadIdx.x;
  if (i < n4) {
    float4 val = *(const float4*)(in + (size_t)i * 4);
    unsigned int p0 = (unsigned int)f2bu(val.x) | ((unsigned int)f2bu(val.y) << 16);
    unsigned int p1 = (unsigned int)f2bu(val.z) | ((unsigned int)f2bu(val.w) << 16);
    uint2 pk; pk.x = p0; pk.y = p1;
    *(uint2*)(out + (size_t)i * 4) = pk;
  }
}

// ---------------------------------------------------------------- shared GEMM core: C = A(bf16) * Bw(bf16)^T
static __device__ __forceinline__ void gemm_core(const unsigned short* __restrict__ Aw,
                                                 const unsigned short* __restrict__ Bw,
                                                 int m0, int n0,
                                                 f32x4 (&acc)[4][4],
                                                 unsigned short (*As)[64], unsigned short (*Bs)[64]) {
  const int K = 1024;
  const int tid = threadIdx.x;
  const int lane = tid & 63, wave = tid >> 6;
  const int wm = wave >> 1, wn = wave & 1;
  const int row16 = lane & 15, kgrp = lane >> 4;
  const int srow = lane >> 3, sslot = (lane & 7) ^ srow;
  const int sw = row16 & 7;

  for (int k0 = 0; k0 < K; k0 += 64) {
#pragma unroll
    for (int i = 0; i < 4; i++) {
      int rr = (wave * 4 + i) * 8 + srow;
      GLD16(Aw + (size_t)(m0 + rr) * K + k0 + sslot * 8, (char*)As + (wave * 4 + i) * 1024);
      GLD16(Bw + (size_t)(n0 + rr) * K + k0 + sslot * 8, (char*)Bs + (wave * 4 + i) * 1024);
    }
    __syncthreads();

#pragma unroll
    for (int kk = 0; kk < 2; kk++) {
      s16x8 af[4], bfr[4];
#pragma unroll
      for (int mi = 0; mi < 4; mi++) {
        int rr = wm * 64 + mi * 16 + row16;
        af[mi] = *(const s16x8*)((char*)&As[rr][0] + ((kk * 4 + kgrp) ^ sw) * 16);
      }
#pragma unroll
      for (int ni = 0; ni < 4; ni++) {
        int rr = wn * 64 + ni * 16 + row16;
        bfr[ni] = *(const s16x8*)((char*)&Bs[rr][0] + ((kk * 4 + kgrp) ^ sw) * 16);
      }
#pragma unroll
      for (int mi = 0; mi < 4; mi++)
#pragma unroll
        for (int ni = 0; ni < 4; ni++)
          acc[mi][ni] = MFMA16(af[mi], bfr[ni], acc[mi][ni]);
    }
    __syncthreads();
  }
}

// fused Q/K/V projection, 1D grid 768, XCD-aware. z=2 writes Vt transposed.
__global__ __launch_bounds__(256) void qkv_gemm(const unsigned short* __restrict__ qc,
                                                const unsigned short* __restrict__ kc,
                                                const unsigned short* __restrict__ vc,
                                                const unsigned short* __restrict__ Wqb,
                                                const unsigned short* __restrict__ Wkb,
                                                const unsigned short* __restrict__ Wvb,
                                                unsigned short* __restrict__ Qb,
                                                unsigned short* __restrict__ Kb,
                                                unsigned short* __restrict__ Vt) {
  __shared__ unsigned short As[128][64];
  __shared__ unsigned short Bs[128][64];
  const int xcd = blockIdx.x & 7, u = blockIdx.x >> 3;   // u 0..95
  const int g = xcd * 12 + (u >> 3);                     // unit 0..95
  const int z = g >> 5, mstrip = g & 31;
  const int m0 = mstrip * 128, n0 = (u & 7) * 128;

  const unsigned short* A = (z == 0) ? qc : (z == 1) ? kc : vc;
  const unsigned short* Bw = (z == 0) ? Wqb : (z == 1) ? Wkb : Wvb;

  f32x4 acc[4][4] = {};
  gemm_core(A, Bw, m0, n0, acc, As, Bs);

  const int lane = threadIdx.x & 63, wave = threadIdx.x >> 6;
  const int wm = wave >> 1, wn = wave & 1;
  const int row16 = lane & 15, kgrp = lane >> 4;

  if (z < 2) {
    unsigned short* C = z ? Kb : Qb;
#pragma unroll
    for (int mi = 0; mi < 4; mi++)
#pragma unroll
      for (int ni = 0; ni < 4; ni++)
#pragma unroll
        for (int r = 0; r < 4; r++) {
          int row = m0 + wm * 64 + mi * 16 + kgrp * 4 + r;
          int col = n0 + wn * 64 + ni * 16 + row16;
          C[(size_t)row * 1024 + col] = f2bu(acc[mi][ni][r]);
        }
  } else {
#pragma unroll
    for (int mi = 0; mi < 4; mi++)
#pragma unroll
      for (int ni = 0; ni < 4; ni++) {
        int mb = m0 + wm * 64 + mi * 16 + kgrp * 4;
        int col = n0 + wn * 64 + ni * 16 + row16;
        int bb = mb >> 11, s = mb & 2047;
        unsigned int p0 = (unsigned int)f2bu(acc[mi][ni][0]) | ((unsigned int)f2bu(acc[mi][ni][1]) << 16);
        unsigned int p1 = (unsigned int)f2bu(acc[mi][ni][2]) | ((unsigned int)f2bu(acc[mi][ni][3]) << 16);
        uint2 pk; pk.x = p0; pk.y = p1;
        *(uint2*)&Vt[(((size_t)(bb * 1024 + col)) << 11) + s] = pk;
      }
  }
}

// output projection: out = attn(bf16) * Wo(bf16)^T, f32 out. 1D grid 256, XCD-aware.
__global__ __launch_bounds__(256) void gemm_wo(const unsigned short* __restrict__ A,
                                               const unsigned short* __restrict__ Bw,
                                               float* __restrict__ C) {
  __shared__ unsigned short As[128][64];
  __shared__ unsigned short Bs[128][64];
  const int xcd = blockIdx.x & 7, u = blockIdx.x >> 3;   // u 0..31
  const int g = xcd * 4 + (u >> 3);                      // m-strip 0..31
  const int m0 = g * 128, n0 = (u & 7) * 128;

  f32x4 acc[4][4] = {};
  gemm_core(A, Bw, m0, n0, acc, As, Bs);

  const int lane = threadIdx.x & 63, wave = threadIdx.x >> 6;
  const int wm = wave >> 1, wn = wave & 1;
  const int row16 = lane & 15, kgrp = lane >> 4;
#pragma unroll
  for (int mi = 0; mi < 4; mi++)
#pragma unroll
    for (int ni = 0; ni < 4; ni++)
#pragma unroll
      for (int r = 0; r < 4; r++) {
        int row = m0 + wm * 64 + mi * 16 + kgrp * 4 + r;
        int col = n0 + wn * 64 + ni * 16 + row16;
        C[(size_t)row * 1024 + col] = acc[mi][ni][r];
      }
}

// ---------------------------------------------------------------- first-unmasked + additive penalty per key
__global__ __launch_bounds__(256) void fu_pen_kernel(const int* __restrict__ mask, int* __restrict__ fu,
                                                     float* __restrict__ pen) {
  const int S = 2048;
  int b = blockIdx.x;
  __shared__ int red[256];
  int best = S;
  for (int k = threadIdx.x; k < S; k += 256) {
    int mv = mask[b * S + k];
    pen[b * S + k] = mv ? 0.0f : -30000.0f;
    if (mv != 0 && k < best) best = k;
  }
  red[threadIdx.x] = best;
  __syncthreads();
  for (int s = 128; s > 0; s >>= 1) {
    if (threadIdx.x < s) red[threadIdx.x] = min(red[threadIdx.x], red[threadIdx.x + s]);
    __syncthreads();
  }
  if (threadIdx.x == 0) fu[b] = red[0];
}

// ---------------------------------------------------------------- V column sums from Vt (deterministic)
__global__ __launch_bounds__(256) void reduce_vt(const unsigned short* __restrict__ Vt,
                                                 float* __restrict__ vsum) {
  __shared__ float red[256];
  const unsigned short* p = Vt + ((size_t)blockIdx.x << 11) + threadIdx.x * 8;
  uint4 u = *(const uint4*)p;
  float s = b2f((unsigned short)(u.x & 0xffff));
  s += b2f((unsigned short)(u.x >> 16));
  s += b2f((unsigned short)(u.y & 0xffff));
  s += b2f((unsigned short)(u.y >> 16));
  s += b2f((unsigned short)(u.z & 0xffff));
  s += b2f((unsigned short)(u.z >> 16));
  s += b2f((unsigned short)(u.w & 0xffff));
  s += b2f((unsigned short)(u.w >> 16));
  red[threadIdx.x] = s;
  __syncthreads();
  for (int st = 128; st > 0; st >>= 1) {
    if (threadIdx.x < st) red[threadIdx.x] += red[threadIdx.x + st];
    __syncthreads();
  }
  if (threadIdx.x == 0) vsum[blockIdx.x] = red[0];
}

// ---------------------------------------------------------------- flash attention v5
// 1024 single-qt blocks, longest-first; exp2-domain softmax; additive mask penalty (FMA);
// causal only on diagonal tile; defer-max skips exact-identity rescales.
__global__ __launch_bounds__(256) void flash_attn5(const unsigned short* __restrict__ Q,
                                                   const unsigned short* __restrict__ Kp,
                                                   const unsigned short* __restrict__ Vt,
                                                   const float* __restrict__ pen,
                                                   const int* __restrict__ fu,
                                                   const float* __restrict__ vsum,
                                                   unsigned short* __restrict__ O) {
  const int S = 2048, DM = 1024;
  const float SCALE2 = 0.125f * 1.4426950408889634f;   // /sqrt(dk) * log2(e)
  const int bid = blockIdx.x;                 // 0..1023
  const int qt = 31 - (bid >> 5);             // longest blocks dispatch first
  const int bh = bid & 31;
  const int b = bh >> 4, h = bh & 15;
  const int tid = threadIdx.x, lane = tid & 63, wave = tid >> 6;
  const int row16 = lane & 15, kgrp = lane >> 4;

  __shared__ unsigned short Ks[2][64][64];   // 16 KB, XOR-swizzled 8B slots
  __shared__ unsigned short Vs[2][64][64];   // 16 KB (V^T tile: rows=d, cols=k), swizzled
  __shared__ unsigned short Ps[4][16][72];   // per-wave P [q][k], padded rows

  const size_t base = ((size_t)b * S) * DM + h * 64;
  const size_t vtb = ((size_t)(b * 1024 + h * 64)) * S;
  const float* penb = pen + b * S;

  const int srow = lane >> 3;
  const int sslot = (lane & 7) ^ srow;
  const int sw = row16 & 7;

  const int q0 = qt * 64 + wave * 16;
  const int qg = q0 + row16;                 // this lane's q row (lane-local)
  const int nt = qt + 1;

  s16x8 qf0 = *(const s16x8*)&Q[base + (size_t)qg * DM + kgrp * 8];
  s16x8 qf1 = *(const s16x8*)&Q[base + (size_t)qg * DM + 32 + kgrp * 8];

  f32x4 oacc[4] = {};
  float m_run = -1e30f, l_run = 0.f;

  auto stage = [&](int t, int bf) {
    const int kb = t * 64;
#pragma unroll
    for (int c2 = 0; c2 < 2; c2++) {
      const int r = wave * 16 + c2 * 8 + srow;
      GLD16(Kp + base + (size_t)(kb + r) * DM + sslot * 8,
            (char*)&Ks[bf][0][0] + (wave * 2 + c2) * 1024);
      GLD16(Vt + vtb + (size_t)r * S + kb + sslot * 8,
            (char*)&Vs[bf][0][0] + (wave * 2 + c2) * 1024);
    }
  };

  stage(0, 0);
  asm volatile("s_waitcnt vmcnt(0)" ::: "memory");
  __syncthreads();

  int cur = 0;
  for (int t = 0; t < nt; ++t) {
    if (t + 1 < nt) stage(t + 1, cur ^ 1);
    const int kb = t * 64;

    // mask penalties (L1-hot broadcast loads, issued early to hide latency)
    float4 pv[4];
#pragma unroll
    for (int nf = 0; nf < 4; nf++)
      pv[nf] = *(const float4*)&penb[kb + nf * 16 + kgrp * 4];

    // S^T = K * Q^T : lane holds scores for q=qg, k = kb + nf*16 + kgrp*4 + r
    f32x4 sc[4];
#pragma unroll
    for (int nf = 0; nf < 4; nf++) {
      const int rr = nf * 16 + row16;
      s16x8 k0 = *(const s16x8*)&Ks[cur][rr][(kgrp ^ sw) * 8];
      s16x8 k1 = *(const s16x8*)&Ks[cur][rr][((4 + kgrp) ^ sw) * 8];
      f32x4 a = {};
      a = MFMA16(k0, qf0, a);
      a = MFMA16(k1, qf1, a);
      sc[nf] = a;
    }

    // scale to log2 domain + additive mask penalty (one FMA per score)
#pragma unroll
    for (int nf = 0; nf < 4; nf++) {
      sc[nf][0] = fmaf(sc[nf][0], SCALE2, pv[nf].x);
      sc[nf][1] = fmaf(sc[nf][1], SCALE2, pv[nf].y);
      sc[nf][2] = fmaf(sc[nf][2], SCALE2, pv[nf].z);
      sc[nf][3] = fmaf(sc[nf][3], SCALE2, pv[nf].w);
    }
    // causal: only the diagonal tile needs it
    if (t == nt - 1) {
#pragma unroll
      for (int nf = 0; nf < 4; nf++) {
        const int kbase = kb + nf * 16 + kgrp * 4;
#pragma unroll
        for (int r = 0; r < 4; r++)
          if (kbase + r > qg) sc[nf][r] = -30000.0f;
      }
    }

    // max: in-lane tree (max3-fusable) + 2 shfl across the 4 lanes sharing q
    float t01 = fmaxf(fmaxf(sc[0][0], sc[0][1]), fmaxf(sc[0][2], sc[0][3]));
    float t23 = fmaxf(fmaxf(sc[1][0], sc[1][1]), fmaxf(sc[1][2], sc[1][3]));
    float t45 = fmaxf(fmaxf(sc[2][0], sc[2][1]), fmaxf(sc[2][2], sc[2][3]));
    float t67 = fmaxf(fmaxf(sc[3][0], sc[3][1]), fmaxf(sc[3][2], sc[3][3]));
    float tmax = fmaxf(fmaxf(t01, t23), fmaxf(t45, t67));
    tmax = fmaxf(tmax, __shfl_xor(tmax, 16));
    tmax = fmaxf(tmax, __shfl_xor(tmax, 32));

    // defer-max: rescale only when the max actually rises (skipped ops are exact identities)
    if (__any(tmax > m_run)) {
      float mnew = fmaxf(m_run, tmax);
      float alpha = __builtin_exp2f(m_run - mnew);
      m_run = mnew;
      l_run *= alpha;
#pragma unroll
      for (int nf2 = 0; nf2 < 4; nf2++)
#pragma unroll
        for (int r = 0; r < 4; r++) oacc[nf2][r] *= alpha;
    }

    float rsum = 0.f;
#pragma unroll
    for (int nf = 0; nf < 4; nf++)
#pragma unroll
      for (int r = 0; r < 4; r++) {
        float p = __builtin_exp2f(sc[nf][r] - m_run);
        sc[nf][r] = p;
        rsum += p;
      }
    rsum += __shfl_xor(rsum, 16);
    rsum += __shfl_xor(rsum, 32);
    l_run += rsum;

    // P pack: 4 consecutive k per nf -> one 8B write each
#pragma unroll
    for (int nf = 0; nf < 4; nf++) {
      uint2 pk;
      pk.x = (unsigned int)f2bu(sc[nf][0]) | ((unsigned int)f2bu(sc[nf][1]) << 16);
      pk.y = (unsigned int)f2bu(sc[nf][2]) | ((unsigned int)f2bu(sc[nf][3]) << 16);
      *(uint2*)&Ps[wave][row16][nf * 16 + kgrp * 4] = pk;
    }
    s16x8 pf0 = *(const s16x8*)&Ps[wave][row16][kgrp * 8];
    s16x8 pf1 = *(const s16x8*)&Ps[wave][row16][32 + kgrp * 8];

    // O^T += V^T * P^T
#pragma unroll
    for (int nf2 = 0; nf2 < 4; nf2++) {
      const int rr = nf2 * 16 + row16;
      s16x8 v0 = *(const s16x8*)&Vs[cur][rr][(kgrp ^ sw) * 8];
      s16x8 v1 = *(const s16x8*)&Vs[cur][rr][((4 + kgrp) ^ sw) * 8];
      oacc[nf2] = MFMA16(v0, pf0, oacc[nf2]);
      oacc[nf2] = MFMA16(v1, pf1, oacc[nf2]);
    }

    asm volatile("s_waitcnt vmcnt(0)" ::: "memory");
    __syncthreads();
    cur ^= 1;
  }

  // epilogue: lane owns q=qg, d = nf2*16 + kgrp*4 + r -> packed bf16 stores
  const int fub = fu[b];
  const float* vs = vsum + b * DM + h * 64;
  const float rl = 1.0f / l_run;
#pragma unroll
  for (int nf2 = 0; nf2 < 4; nf2++) {
    const int d0 = nf2 * 16 + kgrp * 4;
    float v0 = oacc[nf2][0] * rl, v1 = oacc[nf2][1] * rl;
    float v2 = oacc[nf2][2] * rl, v3 = oacc[nf2][3] * rl;
    if (qg < fub) {
      float4 vv = *(const float4*)&vs[d0];
      v0 = vv.x * (1.0f / 2048.0f);
      v1 = vv.y * (1.0f / 2048.0f);
      v2 = vv.z * (1.0f / 2048.0f);
      v3 = vv.w * (1.0f / 2048.0f);
    }
    uint2 pk;
    pk.x = (unsigned int)f2bu(v0) | ((unsigned int)f2bu(v1) << 16);
    pk.y = (unsigned int)f2bu(v2) | ((unsigned int)f2bu(v3) << 16);
    *(uint2*)&O[base + (size_t)qg * DM + d0] = pk;
  }
}

// ---------------------------------------------------------------- launch
extern "C" void kernel_launch(void* const* d_in, const int* in_sizes, int n_in,
                              void* d_out, int out_size, void* d_ws, size_t ws_size,
                              hipStream_t stream) {
  const float* q    = (const float*)d_in[0];
  const float* k    = (const float*)d_in[1];
  const float* v    = (const float*)d_in[2];
  const int*   mask = (const int*)d_in[3];
  const float* Wq   = (const float*)d_in[4];
  const float* Wk   = (const float*)d_in[5];
  const float* Wv   = (const float*)d_in[6];
  const float* Wo   = (const float*)d_in[7];
  float* out = (float*)d_out;
  char* ws = (char*)d_ws;

  unsigned short* Wqb  = (unsigned short*)(ws + (size_t)0);
  unsigned short* Wkb  = (unsigned short*)(ws + ((size_t)2 << 20));
  unsigned short* Wvb  = (unsigned short*)(ws + ((size_t)4 << 20));
  unsigned short* Wob  = (unsigned short*)(ws + ((size_t)6 << 20));
  unsigned short* vc   = (unsigned short*)(ws + ((size_t)8 << 20));   // dead after qkv_gemm
  unsigned short* attn = (unsigned short*)(ws + ((size_t)8 << 20));   // aliases vc
  unsigned short* Qb   = (unsigned short*)(ws + ((size_t)16 << 20));
  unsigned short* Kb   = (unsigned short*)(ws + ((size_t)24 << 20));
  unsigned short* Vt   = (unsigned short*)(ws + ((size_t)32 << 20));
  float* vsum          = (float*)(ws + ((size_t)40 << 20));
  int*   fub           = (int*)(ws + ((size_t)40 << 20) + (64 << 10));
  float* pen           = (float*)(ws + ((size_t)40 << 20) + (68 << 10));
  unsigned short* qc   = (unsigned short*)d_out;                      // d_out as cast scratch
  unsigned short* kc   = (unsigned short*)d_out + 4194304;

  cast_all<<<dim3(4096, 7), 256, 0, stream>>>(q, k, v, Wq, Wk, Wv, Wo,
                                              qc, kc, vc, Wqb, Wkb, Wvb, Wob);

  qkv_gemm<<<768, 256, 0, stream>>>(qc, kc, vc, Wqb, Wkb, Wvb, Qb, Kb, Vt);

  fu_pen_kernel<<<2, 256, 0, stream>>>(mask, fub, pen);
  reduce_vt<<<2048, 256, 0, stream>>>(Vt, vsum);

  flash_attn5<<<1024, 256, 0, stream>>>(Qb, Kb, Vt, pen, fub, vsum, attn);

  gemm_wo<<<256, 256, 0, stream>>>(attn, Wob, out);
}

// Round 9
// 143.334 us; speedup vs baseline: 2.2046x; 1.0105x over previous
//
#include <hip/hip_runtime.h>
#include <hip/hip_bf16.h>
#include <math.h>

typedef __attribute__((ext_vector_type(8))) short s16x8;
typedef __attribute__((ext_vector_type(4))) float f32x4;

#define MFMA16(a,b,c) __builtin_amdgcn_mfma_f32_16x16x32_bf16((a),(b),(c),0,0,0)

#define GLD16(gp, lp) __builtin_amdgcn_global_load_lds( \
  (const __attribute__((address_space(1))) unsigned int*)(gp), \
  (__attribute__((address_space(3))) unsigned int*)(lp), 16, 0, 0)

static __device__ __forceinline__ unsigned short f2bu(float f) {
  __hip_bfloat16 h = __float2bfloat16(f);
  unsigned short u; __builtin_memcpy(&u, &h, 2); return u;
}
static __device__ __forceinline__ float b2f(unsigned short u) {
  unsigned int x = ((unsigned int)u) << 16; float f; __builtin_memcpy(&f, &x, 4); return f;
}

// ---------------------------------------------------------------- cast activations + weights, one launch
__global__ __launch_bounds__(256) void cast_all(const float* __restrict__ q, const float* __restrict__ k,
                                                const float* __restrict__ v,
                                                const float* __restrict__ Wq, const float* __restrict__ Wk,
                                                const float* __restrict__ Wv, const float* __restrict__ Wo,
                                                unsigned short* __restrict__ qc, unsigned short* __restrict__ kc,
                                                unsigned short* __restrict__ vc,
                                                unsigned short* __restrict__ wq, unsigned short* __restrict__ wk,
                                                unsigned short* __restrict__ wv, unsigned short* __restrict__ wo) {
  const int y = blockIdx.y;
  const float* in; unsigned short* out; int n4;
  switch (y) {
    case 0: in = q;  out = qc; n4 = 1048576; break;
    case 1: in = k;  out = kc; n4 = 1048576; break;
    case 2: in = v;  out = vc; n4 = 1048576; break;
    case 3: in = Wq; out = wq; n4 = 262144; break;
    case 4: in = Wk; out = wk; n4 = 262144; break;
    case 5: in = Wv; out = wv; n4 = 262144; break;
    default: in = Wo; out = wo; n4 = 262144; break;
  }
  int i = blockIdx.x * 256 + threadIdx.x;
  if (i < n4) {
    float4 val = *(const float4*)(in + (size_t)i * 4);
    unsigned int p0 = (unsigned int)f2bu(val.x) | ((unsigned int)f2bu(val.y) << 16);
    unsigned int p1 = (unsigned int)f2bu(val.z) | ((unsigned int)f2bu(val.w) << 16);
    uint2 pk; pk.x = p0; pk.y = p1;
    *(uint2*)(out + (size_t)i * 4) = pk;
  }
}

// ---------------------------------------------------------------- shared GEMM core: C = A(bf16) * Bw(bf16)^T
static __device__ __forceinline__ void gemm_core(const unsigned short* __restrict__ Aw,
                                                 const unsigned short* __restrict__ Bw,
                                                 int m0, int n0,
                                                 f32x4 (&acc)[4][4],
                                                 unsigned short (*As)[64], unsigned short (*Bs)[64]) {
  const int K = 1024;
  const int tid = threadIdx.x;
  const int lane = tid & 63, wave = tid >> 6;
  const int wm = wave >> 1, wn = wave & 1;
  const int row16 = lane & 15, kgrp = lane >> 4;
  const int srow = lane >> 3, sslot = (lane & 7) ^ srow;
  const int sw = row16 & 7;

  for (int k0 = 0; k0 < K; k0 += 64) {
#pragma unroll
    for (int i = 0; i < 4; i++) {
      int rr = (wave * 4 + i) * 8 + srow;
      GLD16(Aw + (size_t)(m0 + rr) * K + k0 + sslot * 8, (char*)As + (wave * 4 + i) * 1024);
      GLD16(Bw + (size_t)(n0 + rr) * K + k0 + sslot * 8, (char*)Bs + (wave * 4 + i) * 1024);
    }
    __syncthreads();

#pragma unroll
    for (int kk = 0; kk < 2; kk++) {
      s16x8 af[4], bfr[4];
#pragma unroll
      for (int mi = 0; mi < 4; mi++) {
        int rr = wm * 64 + mi * 16 + row16;
        af[mi] = *(const s16x8*)((char*)&As[rr][0] + ((kk * 4 + kgrp) ^ sw) * 16);
      }
#pragma unroll
      for (int ni = 0; ni < 4; ni++) {
        int rr = wn * 64 + ni * 16 + row16;
        bfr[ni] = *(const s16x8*)((char*)&Bs[rr][0] + ((kk * 4 + kgrp) ^ sw) * 16);
      }
#pragma unroll
      for (int mi = 0; mi < 4; mi++)
#pragma unroll
        for (int ni = 0; ni < 4; ni++)
          acc[mi][ni] = MFMA16(af[mi], bfr[ni], acc[mi][ni]);
    }
    __syncthreads();
  }
}

// fused Q/K/V projection, 1D grid 768, XCD-aware. z=2 writes Vt transposed.
__global__ __launch_bounds__(256) void qkv_gemm(const unsigned short* __restrict__ qc,
                                                const unsigned short* __restrict__ kc,
                                                const unsigned short* __restrict__ vc,
                                                const unsigned short* __restrict__ Wqb,
                                                const unsigned short* __restrict__ Wkb,
                                                const unsigned short* __restrict__ Wvb,
                                                unsigned short* __restrict__ Qb,
                                                unsigned short* __restrict__ Kb,
                                                unsigned short* __restrict__ Vt) {
  __shared__ unsigned short As[128][64];
  __shared__ unsigned short Bs[128][64];
  const int xcd = blockIdx.x & 7, u = blockIdx.x >> 3;   // u 0..95
  const int g = xcd * 12 + (u >> 3);                     // unit 0..95
  const int z = g >> 5, mstrip = g & 31;
  const int m0 = mstrip * 128, n0 = (u & 7) * 128;

  const unsigned short* A = (z == 0) ? qc : (z == 1) ? kc : vc;
  const unsigned short* Bw = (z == 0) ? Wqb : (z == 1) ? Wkb : Wvb;

  f32x4 acc[4][4] = {};
  gemm_core(A, Bw, m0, n0, acc, As, Bs);

  const int lane = threadIdx.x & 63, wave = threadIdx.x >> 6;
  const int wm = wave >> 1, wn = wave & 1;
  const int row16 = lane & 15, kgrp = lane >> 4;

  if (z < 2) {
    unsigned short* C = z ? Kb : Qb;
#pragma unroll
    for (int mi = 0; mi < 4; mi++)
#pragma unroll
      for (int ni = 0; ni < 4; ni++)
#pragma unroll
        for (int r = 0; r < 4; r++) {
          int row = m0 + wm * 64 + mi * 16 + kgrp * 4 + r;
          int col = n0 + wn * 64 + ni * 16 + row16;
          C[(size_t)row * 1024 + col] = f2bu(acc[mi][ni][r]);
        }
  } else {
#pragma unroll
    for (int mi = 0; mi < 4; mi++)
#pragma unroll
      for (int ni = 0; ni < 4; ni++) {
        int mb = m0 + wm * 64 + mi * 16 + kgrp * 4;
        int col = n0 + wn * 64 + ni * 16 + row16;
        int bb = mb >> 11, s = mb & 2047;
        unsigned int p0 = (unsigned int)f2bu(acc[mi][ni][0]) | ((unsigned int)f2bu(acc[mi][ni][1]) << 16);
        unsigned int p1 = (unsigned int)f2bu(acc[mi][ni][2]) | ((unsigned int)f2bu(acc[mi][ni][3]) << 16);
        uint2 pk; pk.x = p0; pk.y = p1;
        *(uint2*)&Vt[(((size_t)(bb * 1024 + col)) << 11) + s] = pk;
      }
  }
}

// output projection: out = attn(bf16) * Wo(bf16)^T, f32 out. 1D grid 256, XCD-aware.
__global__ __launch_bounds__(256) void gemm_wo(const unsigned short* __restrict__ A,
                                               const unsigned short* __restrict__ Bw,
                                               float* __restrict__ C) {
  __shared__ unsigned short As[128][64];
  __shared__ unsigned short Bs[128][64];
  const int xcd = blockIdx.x & 7, u = blockIdx.x >> 3;   // u 0..31
  const int g = xcd * 4 + (u >> 3);                      // m-strip 0..31
  const int m0 = g * 128, n0 = (u & 7) * 128;

  f32x4 acc[4][4] = {};
  gemm_core(A, Bw, m0, n0, acc, As, Bs);

  const int lane = threadIdx.x & 63, wave = threadIdx.x >> 6;
  const int wm = wave >> 1, wn = wave & 1;
  const int row16 = lane & 15, kgrp = lane >> 4;
#pragma unroll
  for (int mi = 0; mi < 4; mi++)
#pragma unroll
    for (int ni = 0; ni < 4; ni++)
#pragma unroll
      for (int r = 0; r < 4; r++) {
        int row = m0 + wm * 64 + mi * 16 + kgrp * 4 + r;
        int col = n0 + wn * 64 + ni * 16 + row16;
        C[(size_t)row * 1024 + col] = acc[mi][ni][r];
      }
}

// ---------------------------------------------------------------- first-unmasked + additive penalty per key
__global__ __launch_bounds__(256) void fu_pen_kernel(const int* __restrict__ mask, int* __restrict__ fu,
                                                     float* __restrict__ pen) {
  const int S = 2048;
  int b = blockIdx.x;
  __shared__ int red[256];
  int best = S;
  for (int k = threadIdx.x; k < S; k += 256) {
    int mv = mask[b * S + k];
    pen[b * S + k] = mv ? 0.0f : -30000.0f;
    if (mv != 0 && k < best) best = k;
  }
  red[threadIdx.x] = best;
  __syncthreads();
  for (int s = 128; s > 0; s >>= 1) {
    if (threadIdx.x < s) red[threadIdx.x] = min(red[threadIdx.x], red[threadIdx.x + s]);
    __syncthreads();
  }
  if (threadIdx.x == 0) fu[b] = red[0];
}

// ---------------------------------------------------------------- V column sums from Vt (deterministic)
__global__ __launch_bounds__(256) void reduce_vt(const unsigned short* __restrict__ Vt,
                                                 float* __restrict__ vsum) {
  __shared__ float red[256];
  const unsigned short* p = Vt + ((size_t)blockIdx.x << 11) + threadIdx.x * 8;
  uint4 u = *(const uint4*)p;
  float s = b2f((unsigned short)(u.x & 0xffff));
  s += b2f((unsigned short)(u.x >> 16));
  s += b2f((unsigned short)(u.y & 0xffff));
  s += b2f((unsigned short)(u.y >> 16));
  s += b2f((unsigned short)(u.z & 0xffff));
  s += b2f((unsigned short)(u.z >> 16));
  s += b2f((unsigned short)(u.w & 0xffff));
  s += b2f((unsigned short)(u.w >> 16));
  red[threadIdx.x] = s;
  __syncthreads();
  for (int st = 128; st > 0; st >>= 1) {
    if (threadIdx.x < st) red[threadIdx.x] += red[threadIdx.x + st];
    __syncthreads();
  }
  if (threadIdx.x == 0) vsum[blockIdx.x] = red[0];
}

// ---------------------------------------------------------------- flash attention v6b
// v6 with the Ps overflow FIXED: Ps[4][16][64] (full 64-short rows), XOR slot swizzle
// (same scheme as Ks/Vs) instead of padding. LDS = 40960 B exactly -> 4 blocks/CU.
__global__ __launch_bounds__(256) void flash_attn6(const unsigned short* __restrict__ Q,
                                                   const unsigned short* __restrict__ Kp,
                                                   const unsigned short* __restrict__ Vt,
                                                   const float* __restrict__ pen,
                                                   const int* __restrict__ fu,
                                                   const float* __restrict__ vsum,
                                                   unsigned short* __restrict__ O) {
  const int S = 2048, DM = 1024;
  const float SCALE2 = 0.125f * 1.4426950408889634f;   // /sqrt(dk) * log2(e)
  const int bid = blockIdx.x;                 // 0..1023
  const int qt = 31 - (bid >> 5);             // longest blocks dispatch first
  const int bh = bid & 31;
  const int b = bh >> 4, h = bh & 15;
  const int tid = threadIdx.x, lane = tid & 63, wave = tid >> 6;
  const int row16 = lane & 15, kgrp = lane >> 4;

  __shared__ unsigned short Ks[2][64][64];   // 16 KB, XOR-swizzled 8B slots
  __shared__ unsigned short Vs[2][64][64];   // 16 KB (V^T tile), swizzled
  __shared__ unsigned short Ps[4][16][64];   // 8 KB per-wave P [q][k], XOR-swizzled slots

  const size_t base = ((size_t)b * S) * DM + h * 64;
  const size_t vtb = ((size_t)(b * 1024 + h * 64)) * S;
  const float* penb = pen + b * S;

  const int srow = lane >> 3;
  const int sslot = (lane & 7) ^ srow;
  const int sw = row16 & 7;

  const int q0 = qt * 64 + wave * 16;
  const int qg = q0 + row16;                 // this lane's q row (lane-local)
  const int nt = qt + 1;

  s16x8 qf0 = *(const s16x8*)&Q[base + (size_t)qg * DM + kgrp * 8];
  s16x8 qf1 = *(const s16x8*)&Q[base + (size_t)qg * DM + 32 + kgrp * 8];

  // constant bf16 1.0 A-fragment for the l row-sum MFMA
  const short ONE = 0x3F80;
  const s16x8 ones8 = {ONE, ONE, ONE, ONE, ONE, ONE, ONE, ONE};

  f32x4 oacc[4] = {};
  f32x4 lacc = {};                           // lacc[*] = running sum_k P[qg][k] (4 equal copies)
  float m_run = -1e30f;

  auto stage = [&](int t, int bf) {
    const int kb = t * 64;
#pragma unroll
    for (int c2 = 0; c2 < 2; c2++) {
      const int r = wave * 16 + c2 * 8 + srow;
      GLD16(Kp + base + (size_t)(kb + r) * DM + sslot * 8,
            (char*)&Ks[bf][0][0] + (wave * 2 + c2) * 1024);
      GLD16(Vt + vtb + (size_t)r * S + kb + sslot * 8,
            (char*)&Vs[bf][0][0] + (wave * 2 + c2) * 1024);
    }
  };

  stage(0, 0);
  asm volatile("s_waitcnt vmcnt(0)" ::: "memory");
  __syncthreads();

  int cur = 0;
  for (int t = 0; t < nt; ++t) {
    if (t + 1 < nt) stage(t + 1, cur ^ 1);
    const int kb = t * 64;

    // mask penalties (L1-hot broadcast loads, issued early)
    float4 pv[4];
#pragma unroll
    for (int nf = 0; nf < 4; nf++)
      pv[nf] = *(const float4*)&penb[kb + nf * 16 + kgrp * 4];

    // S^T = K * Q^T : lane holds scores for q=qg, k = kb + nf*16 + kgrp*4 + r
    f32x4 sc[4];
    __builtin_amdgcn_s_setprio(1);
#pragma unroll
    for (int nf = 0; nf < 4; nf++) {
      const int rr = nf * 16 + row16;
      s16x8 k0 = *(const s16x8*)&Ks[cur][rr][(kgrp ^ sw) * 8];
      s16x8 k1 = *(const s16x8*)&Ks[cur][rr][((4 + kgrp) ^ sw) * 8];
      f32x4 a = {};
      a = MFMA16(k0, qf0, a);
      a = MFMA16(k1, qf1, a);
      sc[nf] = a;
    }
    __builtin_amdgcn_s_setprio(0);

    // scale to log2 domain + additive mask penalty (one FMA per score)
#pragma unroll
    for (int nf = 0; nf < 4; nf++) {
      sc[nf][0] = fmaf(sc[nf][0], SCALE2, pv[nf].x);
      sc[nf][1] = fmaf(sc[nf][1], SCALE2, pv[nf].y);
      sc[nf][2] = fmaf(sc[nf][2], SCALE2, pv[nf].z);
      sc[nf][3] = fmaf(sc[nf][3], SCALE2, pv[nf].w);
    }
    // causal: only the diagonal tile needs it
    if (t == nt - 1) {
#pragma unroll
      for (int nf = 0; nf < 4; nf++) {
        const int kbase = kb + nf * 16 + kgrp * 4;
#pragma unroll
        for (int r = 0; r < 4; r++)
          if (kbase + r > qg) sc[nf][r] = -30000.0f;
      }
    }

    // max: in-lane tree + 2 shfl across the 4 lanes sharing q
    float t01 = fmaxf(fmaxf(sc[0][0], sc[0][1]), fmaxf(sc[0][2], sc[0][3]));
    float t23 = fmaxf(fmaxf(sc[1][0], sc[1][1]), fmaxf(sc[1][2], sc[1][3]));
    float t45 = fmaxf(fmaxf(sc[2][0], sc[2][1]), fmaxf(sc[2][2], sc[2][3]));
    float t67 = fmaxf(fmaxf(sc[3][0], sc[3][1]), fmaxf(sc[3][2], sc[3][3]));
    float tmax = fmaxf(fmaxf(t01, t23), fmaxf(t45, t67));
    tmax = fmaxf(tmax, __shfl_xor(tmax, 16));
    tmax = fmaxf(tmax, __shfl_xor(tmax, 32));

    // defer-max: rescale only when the max actually rises (skipped ops are exact identities)
    if (__any(tmax > m_run)) {
      float mnew = fmaxf(m_run, tmax);
      float alpha = __builtin_exp2f(m_run - mnew);
      m_run = mnew;
      lacc[0] *= alpha; lacc[1] *= alpha; lacc[2] *= alpha; lacc[3] *= alpha;
#pragma unroll
      for (int nf2 = 0; nf2 < 4; nf2++)
#pragma unroll
        for (int r = 0; r < 4; r++) oacc[nf2][r] *= alpha;
    }

#pragma unroll
    for (int nf = 0; nf < 4; nf++)
#pragma unroll
      for (int r = 0; r < 4; r++)
        sc[nf][r] = __builtin_exp2f(sc[nf][r] - m_run);

    // P pack -> XOR-swizzled Ps: logical 16B slot (nf*2 + kgrp/2), half (kgrp&1)
#pragma unroll
    for (int nf = 0; nf < 4; nf++) {
      uint2 pk;
      pk.x = (unsigned int)f2bu(sc[nf][0]) | ((unsigned int)f2bu(sc[nf][1]) << 16);
      pk.y = (unsigned int)f2bu(sc[nf][2]) | ((unsigned int)f2bu(sc[nf][3]) << 16);
      const int slot = (nf * 2 + (kgrp >> 1)) ^ sw;
      *(uint2*)((char*)&Ps[wave][row16][0] + slot * 16 + (kgrp & 1) * 8) = pk;
    }
    s16x8 pf0 = *(const s16x8*)((char*)&Ps[wave][row16][0] + (kgrp ^ sw) * 16);
    s16x8 pf1 = *(const s16x8*)((char*)&Ps[wave][row16][0] + ((4 + kgrp) ^ sw) * 16);

    // O^T += V^T * P^T; l += 1^T * P^T (row-sum on the matrix pipe)
    __builtin_amdgcn_s_setprio(1);
    lacc = MFMA16(ones8, pf0, lacc);
    lacc = MFMA16(ones8, pf1, lacc);
#pragma unroll
    for (int nf2 = 0; nf2 < 4; nf2++) {
      const int rr = nf2 * 16 + row16;
      s16x8 v0 = *(const s16x8*)&Vs[cur][rr][(kgrp ^ sw) * 8];
      s16x8 v1 = *(const s16x8*)&Vs[cur][rr][((4 + kgrp) ^ sw) * 8];
      oacc[nf2] = MFMA16(v0, pf0, oacc[nf2]);
      oacc[nf2] = MFMA16(v1, pf1, oacc[nf2]);
    }
    __builtin_amdgcn_s_setprio(0);

    asm volatile("s_waitcnt vmcnt(0)" ::: "memory");
    __syncthreads();
    cur ^= 1;
  }

  // epilogue: lane owns q=qg, d = nf2*16 + kgrp*4 + r -> packed bf16 stores
  const int fub = fu[b];
  const float* vs = vsum + b * DM + h * 64;
  const float rl = 1.0f / lacc[0];
#pragma unroll
  for (int nf2 = 0; nf2 < 4; nf2++) {
    const int d0 = nf2 * 16 + kgrp * 4;
    float v0 = oacc[nf2][0] * rl, v1 = oacc[nf2][1] * rl;
    float v2 = oacc[nf2][2] * rl, v3 = oacc[nf2][3] * rl;
    if (qg < fub) {
      float4 vv = *(const float4*)&vs[d0];
      v0 = vv.x * (1.0f / 2048.0f);
      v1 = vv.y * (1.0f / 2048.0f);
      v2 = vv.z * (1.0f / 2048.0f);
      v3 = vv.w * (1.0f / 2048.0f);
    }
    uint2 pk;
    pk.x = (unsigned int)f2bu(v0) | ((unsigned int)f2bu(v1) << 16);
    pk.y = (unsigned int)f2bu(v2) | ((unsigned int)f2bu(v3) << 16);
    *(uint2*)&O[base + (size_t)qg * DM + d0] = pk;
  }
}

// ---------------------------------------------------------------- launch
extern "C" void kernel_launch(void* const* d_in, const int* in_sizes, int n_in,
                              void* d_out, int out_size, void* d_ws, size_t ws_size,
                              hipStream_t stream) {
  const float* q    = (const float*)d_in[0];
  const float* k    = (const float*)d_in[1];
  const float* v    = (const float*)d_in[2];
  const int*   mask = (const int*)d_in[3];
  const float* Wq   = (const float*)d_in[4];
  const float* Wk   = (const float*)d_in[5];
  const float* Wv   = (const float*)d_in[6];
  const float* Wo   = (const float*)d_in[7];
  float* out = (float*)d_out;
  char* ws = (char*)d_ws;

  unsigned short* Wqb  = (unsigned short*)(ws + (size_t)0);
  unsigned short* Wkb  = (unsigned short*)(ws + ((size_t)2 << 20));
  unsigned short* Wvb  = (unsigned short*)(ws + ((size_t)4 << 20));
  unsigned short* Wob  = (unsigned short*)(ws + ((size_t)6 << 20));
  unsigned short* vc   = (unsigned short*)(ws + ((size_t)8 << 20));   // dead after qkv_gemm
  unsigned short* attn = (unsigned short*)(ws + ((size_t)8 << 20));   // aliases vc
  unsigned short* Qb   = (unsigned short*)(ws + ((size_t)16 << 20));
  unsigned short* Kb   = (unsigned short*)(ws + ((size_t)24 << 20));
  unsigned short* Vt   = (unsigned short*)(ws + ((size_t)32 << 20));
  float* vsum          = (float*)(ws + ((size_t)40 << 20));
  int*   fub           = (int*)(ws + ((size_t)40 << 20) + (64 << 10));
  float* pen           = (float*)(ws + ((size_t)40 << 20) + (68 << 10));
  unsigned short* qc   = (unsigned short*)d_out;                      // d_out as cast scratch
  unsigned short* kc   = (unsigned short*)d_out + 4194304;

  cast_all<<<dim3(4096, 7), 256, 0, stream>>>(q, k, v, Wq, Wk, Wv, Wo,
                                              qc, kc, vc, Wqb, Wkb, Wvb, Wob);

  qkv_gemm<<<768, 256, 0, stream>>>(qc, kc, vc, Wqb, Wkb, Wvb, Qb, Kb, Vt);

  fu_pen_kernel<<<2, 256, 0, stream>>>(mask, fub, pen);
  reduce_vt<<<2048, 256, 0, stream>>>(Vt, vsum);

  flash_attn6<<<1024, 256, 0, stream>>>(Qb, Kb, Vt, pen, fub, vsum, attn);

  gemm_wo<<<256, 256, 0, stream>>>(attn, Wob, out);
}